// Round 12
// baseline (367.408 us; speedup 1.0000x reference)
//
#include <hip/hip_runtime.h>
#include <cstddef>
#include <cstdint>

constexpr int Bn = 8;
constexpr int Ln = 2048;
constexpr int Dn = 1024;
constexpr float MASKED_VAL = -2147483648.0f;  // -2^31

typedef unsigned short u16;
typedef unsigned int   u32;
typedef __attribute__((ext_vector_type(8))) __bf16 bf16x8;
typedef __attribute__((ext_vector_type(4))) float  f32x4;

__device__ __forceinline__ u16 f2bf(float x) {
    u32 u = __float_as_uint(x);
    u += 0x7FFFu + ((u >> 16) & 1u);
    return (u16)(u >> 16);
}
__device__ __forceinline__ float bf2f(u16 h) {
    return __uint_as_float(((u32)h) << 16);
}
__device__ __forceinline__ u32 pack2(float a, float b) {
    return (u32)f2bf(a) | ((u32)f2bf(b) << 16);
}
__device__ __forceinline__ int rup(int x, int m) { return (x + m - 1) & ~(m - 1); }

__device__ __forceinline__ void gload16(const void* g, void* l) {
    typedef const __attribute__((address_space(1))) unsigned int* gp_t;
    typedef __attribute__((address_space(3))) unsigned int* lp_t;
    __builtin_amdgcn_global_load_lds((gp_t)g, (lp_t)l, 16, 0, 0);
}

#define MFMA16(a, b, c) __builtin_amdgcn_mfma_f32_16x16x32_bf16((a), (b), (c), 0, 0, 0)

// ---------------------------------------------------------------------------
// prep: per batch, compaction tables. kidx (padded w/ last valid), kpos
// (-1 if masked), qidx (padded w/ 0), qpos (-1 if masked), counts.
// ---------------------------------------------------------------------------
__global__ __launch_bounds__(256) void prep_kernel(
    const int* __restrict__ k_mask, const int* __restrict__ q_mask,
    int* __restrict__ kidx, int* __restrict__ kpos,
    int* __restrict__ qidx, int* __restrict__ qpos, int* __restrict__ cnts)
{
    __shared__ int sc[256];
    __shared__ int lastv;
    const int b = blockIdx.x, t = threadIdx.x;
    for (int pass = 0; pass < 2; ++pass) {
        const int* msk = (pass ? q_mask : k_mask) + b * Ln;
        int* idx = (pass ? qidx : kidx) + b * Ln;
        int* pos = (pass ? qpos : kpos) + b * Ln;
        int f[8], s = 0;
        #pragma unroll
        for (int j = 0; j < 8; ++j) { f[j] = (msk[t * 8 + j] != 0) ? 1 : 0; s += f[j]; }
        sc[t] = s;
        __syncthreads();
        #pragma unroll
        for (int o = 1; o < 256; o <<= 1) {
            int v = (t >= o) ? sc[t - o] : 0;
            __syncthreads();
            sc[t] += v;
            __syncthreads();
        }
        int incl = sc[t];
        int total = sc[255];
        int p = incl - s;
        #pragma unroll
        for (int j = 0; j < 8; ++j) {
            pos[t * 8 + j] = f[j] ? p : -1;
            if (f[j]) { idx[p] = t * 8 + j; ++p; }
        }
        __syncthreads();
        if (t == 0) {
            cnts[b * 2 + pass] = total;
            lastv = (total > 0) ? idx[total - 1] : 0;
        }
        __syncthreads();
        int padv = (pass == 0) ? lastv : 0;
        for (int e2 = total + t; e2 < Ln; e2 += 256) idx[e2] = padv;
        __syncthreads();
    }
}

// ---------------------------------------------------------------------------
// wprep: fused weight prep in one launch.
//   blocks [0,512):    wtrans Wq/Wk fp32 -> Wqt/Wkt bf16 [d][e]
//   blocks [512,1024): convert Wv -> Wvb bf16
//   blocks [1024,1032): wvec from fp32: w1[d]=sum_e Wq[e][d]bk[e],
//                       w2[d]=sum_e Wk[e][d]bq[e]  (coalesced column blocks)
//   block 1032:        cbuf[0] = bq.bk
// ---------------------------------------------------------------------------
__global__ __launch_bounds__(256) void wprep_kernel(
    const float* __restrict__ Wq, const float* __restrict__ Wk, const float* __restrict__ Wv,
    const float* __restrict__ bq, const float* __restrict__ bk,
    u16* __restrict__ Wqt, u16* __restrict__ Wkt, u16* __restrict__ Wvb,
    float* __restrict__ w1, float* __restrict__ w2, float* __restrict__ cbuf)
{
    __shared__ float tile[64][68];
    const int blk = blockIdx.x;
    const int t = threadIdx.x;

    if (blk < 512) {
        const float* src = (blk >= 256) ? Wk : Wq;
        u16* dst = (blk >= 256) ? Wkt : Wqt;
        const int rem = blk & 255;
        const int e0 = (rem >> 4) * 64, d0 = (rem & 15) * 64;
        const int r = t >> 2, cq = (t & 3) * 16;
        const float* s = src + (size_t)(e0 + r) * Dn + d0 + cq;
        #pragma unroll
        for (int i = 0; i < 4; ++i)
            *(float4*)&tile[r][cq + i * 4] = *(const float4*)(s + i * 4);
        __syncthreads();
        u32 o[8];
        #pragma unroll
        for (int i = 0; i < 8; ++i)
            o[i] = pack2(tile[cq + 2 * i][r], tile[cq + 2 * i + 1][r]);
        u16* d = dst + (size_t)(d0 + r) * Dn + e0 + cq;
        *(uint4*)(d)     = make_uint4(o[0], o[1], o[2], o[3]);
        *(uint4*)(d + 8) = make_uint4(o[4], o[5], o[6], o[7]);
    } else if (blk < 1024) {
        int i = ((blk - 512) * 256 + t) * 8;
        float f[8];
        *(float4*)&f[0] = *(const float4*)(Wv + i);
        *(float4*)&f[4] = *(const float4*)(Wv + i + 4);
        u32 H[4];
        #pragma unroll
        for (int j = 0; j < 4; ++j) H[j] = pack2(f[2*j], f[2*j+1]);
        *(uint4*)(Wvb + i) = make_uint4(H[0], H[1], H[2], H[3]);
    } else if (blk < 1032) {
        const int rel = blk - 1024;
        const float* W = (rel >> 2) ? Wk : Wq;
        const float* vec = (rel >> 2) ? bq : bk;
        float* out = (rel >> 2) ? w2 : w1;
        const int dd = (rel & 3) * 256 + t;
        float s = 0.f;
        for (int e = 0; e < Dn; ++e) s += W[(size_t)e * Dn + dd] * vec[e];
        out[dd] = s;
    } else {
        if (t < 64) {
            float s = 0.f;
            #pragma unroll
            for (int i = 0; i < 16; ++i) s += bq[t + 64 * i] * bk[t + 64 * i];
            #pragma unroll
            for (int o = 32; o; o >>= 1) s += __shfl_xor(s, o, 64);
            if (t == 0) cbuf[0] = s;
        }
    }
}

// ---------------------------------------------------------------------------
// convq: one block per (b,l) row. Converts Q row -> Xq bf16 AND computes
// u[row] = bf16(Q[row,:]).w1 + c  (block reduce) in the same pass.
// ---------------------------------------------------------------------------
__global__ __launch_bounds__(256) void convq_kernel(
    const float* __restrict__ Q, const float* __restrict__ w1,
    const float* __restrict__ cbuf, u16* __restrict__ Xq, float* __restrict__ u)
{
    __shared__ float red[4];
    const int row = blockIdx.x;
    const int t = threadIdx.x;
    float4 f = *(const float4*)(Q + (size_t)row * Dn + t * 4);
    u32 p0 = pack2(f.x, f.y), p1 = pack2(f.z, f.w);
    *(uint2*)(Xq + (size_t)row * Dn + t * 4) = make_uint2(p0, p1);

    float4 w = *(const float4*)(w1 + t * 4);
    float s = bf2f((u16)(p0 & 0xFFFFu)) * w.x + bf2f((u16)(p0 >> 16)) * w.y
            + bf2f((u16)(p1 & 0xFFFFu)) * w.z + bf2f((u16)(p1 >> 16)) * w.w;
    #pragma unroll
    for (int o = 32; o; o >>= 1) s += __shfl_xor(s, o, 64);
    if ((t & 63) == 0) red[t >> 6] = s;
    __syncthreads();
    if (t == 0) u[row] = red[0] + red[1] + red[2] + red[3] + cbuf[0];
}

// ---------------------------------------------------------------------------
// convkv: one block per (compacted row j, y, b). y=0: K -> Xkc (+ vc dot
// with w2); y=1: V -> Vc. Only rows j < rup(kc,128).
// ---------------------------------------------------------------------------
__global__ __launch_bounds__(256) void convkv_kernel(
    const float* __restrict__ K, const float* __restrict__ V,
    const int* __restrict__ kidx, const int* __restrict__ cnts,
    const float* __restrict__ w2, u16* __restrict__ Xkc, u16* __restrict__ Vc,
    float* __restrict__ vc)
{
    __shared__ float red[4];
    const int b = blockIdx.z, j = blockIdx.x, y = blockIdx.y;
    if (j >= rup(cnts[b * 2], 128)) return;
    const int srow = kidx[b * Ln + j];
    const int t = threadIdx.x;
    float4 f = *(const float4*)((y ? V : K) + ((size_t)b * Ln + srow) * Dn + t * 4);
    u32 p0 = pack2(f.x, f.y), p1 = pack2(f.z, f.w);
    *(uint2*)((y ? Vc : Xkc) + ((size_t)b * Ln + j) * Dn + t * 4) = make_uint2(p0, p1);

    if (y == 0) {
        float4 w = *(const float4*)(w2 + t * 4);
        float s = bf2f((u16)(p0 & 0xFFFFu)) * w.x + bf2f((u16)(p0 >> 16)) * w.y
                + bf2f((u16)(p1 & 0xFFFFu)) * w.z + bf2f((u16)(p1 >> 16)) * w.w;
        #pragma unroll
        for (int o = 32; o; o >>= 1) s += __shfl_xor(s, o, 64);
        if ((t & 63) == 0) red[t >> 6] = s;
        __syncthreads();
        if (t == 0) vc[b * Ln + j] = red[0] + red[1] + red[2] + red[3];
    }
}

// ---------------------------------------------------------------------------
// mgemm: C[m][n] = sum_e A[m,e] * B[n,e]  (1024x1024x1024, bf16 out).
// Called with (Wqt, Wkt) -> Mb[m][n] = (Wq^T Wk)[m][n]  (row-major M).
// ---------------------------------------------------------------------------
__global__ __launch_bounds__(256) void mgemm_kernel(
    const u16* __restrict__ A, const u16* __restrict__ B, u16* __restrict__ C)
{
    __shared__ __align__(16) unsigned char As[128 * 128];
    __shared__ __align__(16) unsigned char Bs[128 * 128];

    const int m0 = blockIdx.y * 128, n0 = blockIdx.x * 128;
    const int tid = threadIdx.x, lane = tid & 63, wid = tid >> 6;
    const int wm = (wid >> 1) * 64, wn = (wid & 1) * 64;

    const u16* gA[4]; const u16* gB[4]; int ldsOff[4];
    #pragma unroll
    for (int q = 0; q < 4; ++q) {
        int c = wid * 4 + q;
        int row = c * 8 + (lane >> 3);
        int sig = (lane & 7) ^ (row & 7);
        gA[q] = A + (size_t)(m0 + row) * Dn + sig * 8;
        gB[q] = B + (size_t)(n0 + row) * Dn + sig * 8;
        ldsOff[q] = c * 1024;
    }

    f32x4 acc[4][4];
    const f32x4 z4 = {0.f, 0.f, 0.f, 0.f};
    #pragma unroll
    for (int i = 0; i < 4; ++i)
        #pragma unroll
        for (int j = 0; j < 4; ++j) acc[i][j] = z4;

    for (int k0 = 0; k0 < Dn; k0 += 64) {
        #pragma unroll
        for (int q = 0; q < 4; ++q) {
            gload16(gA[q], As + ldsOff[q]);
            gload16(gB[q], Bs + ldsOff[q]);
            gA[q] += 64; gB[q] += 64;
        }
        __syncthreads();

        const int sh = lane >> 4;
        #pragma unroll
        for (int s = 0; s < 2; ++s) {
            bf16x8 af[4], bf[4];
            #pragma unroll
            for (int i = 0; i < 4; ++i) {
                int row = wm + i * 16 + (lane & 15);
                af[i] = *(const bf16x8*)(As + row * 128 + (((s * 4 + sh) ^ (row & 7)) << 4));
            }
            #pragma unroll
            for (int j = 0; j < 4; ++j) {
                int row = wn + j * 16 + (lane & 15);
                bf[j] = *(const bf16x8*)(Bs + row * 128 + (((s * 4 + sh) ^ (row & 7)) << 4));
            }
            #pragma unroll
            for (int i = 0; i < 4; ++i)
                #pragma unroll
                for (int j = 0; j < 4; ++j)
                    acc[i][j] = MFMA16(af[i], bf[j], acc[i][j]);
        }
        __syncthreads();
    }

    #pragma unroll
    for (int i = 0; i < 4; ++i) {
        #pragma unroll
        for (int r = 0; r < 4; ++r) {
            int m = m0 + wm + i * 16 + (lane >> 4) * 4 + r;
            u16* oh = C + (size_t)m * Dn + n0 + wn;
            #pragma unroll
            for (int j = 0; j < 4; ++j)
                oh[j * 16 + (lane & 15)] = f2bf(acc[i][j][r]);
        }
    }
}

// ---------------------------------------------------------------------------
// gt: Gt[b][j][:] = Xkc[b][j][:] @ Mb^T  (compacted rows only, no bias)
// ---------------------------------------------------------------------------
__global__ __launch_bounds__(256) void gt_kernel(
    const u16* __restrict__ Xkc, const u16* __restrict__ Mb,
    const int* __restrict__ cnts, u16* __restrict__ Gt)
{
    __shared__ __align__(16) unsigned char As[128 * 128];
    __shared__ __align__(16) unsigned char Bs[128 * 128];

    const int b = blockIdx.z;
    const int kc_b = cnts[b * 2];
    const int m0 = blockIdx.y * 128;
    if (m0 >= rup(kc_b, 128)) return;
    const int n0 = blockIdx.x * 128;
    const int tid = threadIdx.x, lane = tid & 63, wid = tid >> 6;
    const int wm = (wid >> 1) * 64, wn = (wid & 1) * 64;

    const u16* Xkc_b = Xkc + (size_t)b * Ln * Dn;

    const u16* gA[4]; const u16* gB[4]; int ldsOff[4];
    #pragma unroll
    for (int q = 0; q < 4; ++q) {
        int c = wid * 4 + q;
        int row = c * 8 + (lane >> 3);
        int sig = (lane & 7) ^ (row & 7);
        gA[q] = Xkc_b + (size_t)(m0 + row) * Dn + sig * 8;
        gB[q] = Mb + (size_t)(n0 + row) * Dn + sig * 8;
        ldsOff[q] = c * 1024;
    }

    f32x4 acc[4][4];
    const f32x4 z4 = {0.f, 0.f, 0.f, 0.f};
    #pragma unroll
    for (int i = 0; i < 4; ++i)
        #pragma unroll
        for (int j = 0; j < 4; ++j) acc[i][j] = z4;

    for (int k0 = 0; k0 < Dn; k0 += 64) {
        #pragma unroll
        for (int q = 0; q < 4; ++q) {
            gload16(gA[q], As + ldsOff[q]);
            gload16(gB[q], Bs + ldsOff[q]);
            gA[q] += 64; gB[q] += 64;
        }
        __syncthreads();

        const int sh = lane >> 4;
        #pragma unroll
        for (int s = 0; s < 2; ++s) {
            bf16x8 af[4], bf[4];
            #pragma unroll
            for (int i = 0; i < 4; ++i) {
                int row = wm + i * 16 + (lane & 15);
                af[i] = *(const bf16x8*)(As + row * 128 + (((s * 4 + sh) ^ (row & 7)) << 4));
            }
            #pragma unroll
            for (int j = 0; j < 4; ++j) {
                int row = wn + j * 16 + (lane & 15);
                bf[j] = *(const bf16x8*)(Bs + row * 128 + (((s * 4 + sh) ^ (row & 7)) << 4));
            }
            #pragma unroll
            for (int i = 0; i < 4; ++i)
                #pragma unroll
                for (int j = 0; j < 4; ++j)
                    acc[i][j] = MFMA16(af[i], bf[j], acc[i][j]);
        }
        __syncthreads();
    }

    u16* Gt_b = Gt + (size_t)b * Ln * Dn;
    #pragma unroll
    for (int i = 0; i < 4; ++i) {
        #pragma unroll
        for (int r = 0; r < 4; ++r) {
            int m = m0 + wm + i * 16 + (lane >> 4) * 4 + r;
            u16* oh = Gt_b + (size_t)m * Dn + n0 + wn;
            #pragma unroll
            for (int j = 0; j < 4; ++j)
                oh[j * 16 + (lane & 15)] = f2bf(acc[i][j][r]);
        }
    }
}

// ---------------------------------------------------------------------------
// projv: Vhc[b][j][:] = Vc[b][j][:] @ Wvb^T + bv (compacted rows, linear A).
// ---------------------------------------------------------------------------
__global__ __launch_bounds__(256) void projv_kernel(
    const u16* __restrict__ Vc, const u16* __restrict__ Wvb,
    const float* __restrict__ bv, const int* __restrict__ cnts,
    u16* __restrict__ Vhc)
{
    __shared__ __align__(16) unsigned char As[128 * 128];
    __shared__ __align__(16) unsigned char Bs[128 * 128];

    const int b = blockIdx.z;
    const int kc_b = cnts[b * 2];
    const int m0 = blockIdx.y * 128;
    if (m0 >= rup(kc_b, 128)) return;
    const int n0 = blockIdx.x * 128;
    const int tid = threadIdx.x, lane = tid & 63, wid = tid >> 6;
    const int wm = (wid >> 1) * 64, wn = (wid & 1) * 64;

    const u16* Vc_b = Vc + (size_t)b * Ln * Dn;

    const u16* gA[4]; const u16* gB[4]; int ldsOff[4];
    #pragma unroll
    for (int q = 0; q < 4; ++q) {
        int c = wid * 4 + q;
        int row = c * 8 + (lane >> 3);
        int sig = (lane & 7) ^ (row & 7);
        gA[q] = Vc_b + (size_t)(m0 + row) * Dn + sig * 8;
        gB[q] = Wvb + (size_t)(n0 + row) * Dn + sig * 8;
        ldsOff[q] = c * 1024;
    }

    f32x4 acc[4][4];
    const f32x4 z4 = {0.f, 0.f, 0.f, 0.f};
    #pragma unroll
    for (int i = 0; i < 4; ++i)
        #pragma unroll
        for (int j = 0; j < 4; ++j) acc[i][j] = z4;

    for (int k0 = 0; k0 < Dn; k0 += 64) {
        #pragma unroll
        for (int q = 0; q < 4; ++q) {
            gload16(gA[q], As + ldsOff[q]);
            gload16(gB[q], Bs + ldsOff[q]);
            gA[q] += 64; gB[q] += 64;
        }
        __syncthreads();

        const int sh = lane >> 4;
        #pragma unroll
        for (int s = 0; s < 2; ++s) {
            bf16x8 af[4], bf[4];
            #pragma unroll
            for (int i = 0; i < 4; ++i) {
                int row = wm + i * 16 + (lane & 15);
                af[i] = *(const bf16x8*)(As + row * 128 + (((s * 4 + sh) ^ (row & 7)) << 4));
            }
            #pragma unroll
            for (int j = 0; j < 4; ++j) {
                int row = wn + j * 16 + (lane & 15);
                bf[j] = *(const bf16x8*)(Bs + row * 128 + (((s * 4 + sh) ^ (row & 7)) << 4));
            }
            #pragma unroll
            for (int i = 0; i < 4; ++i)
                #pragma unroll
                for (int j = 0; j < 4; ++j)
                    acc[i][j] = MFMA16(af[i], bf[j], acc[i][j]);
        }
        __syncthreads();
    }

    float bv4[4];
    #pragma unroll
    for (int j = 0; j < 4; ++j) bv4[j] = bv[n0 + wn + j * 16 + (lane & 15)];
    u16* Vhc_b = Vhc + (size_t)b * Ln * Dn;
    #pragma unroll
    for (int i = 0; i < 4; ++i) {
        #pragma unroll
        for (int r = 0; r < 4; ++r) {
            int m = m0 + wm + i * 16 + (lane >> 4) * 4 + r;
            u16* oh = Vhc_b + (size_t)m * Dn + n0 + wn;
            #pragma unroll
            for (int j = 0; j < 4; ++j)
                oh[j * 16 + (lane & 15)] = f2bf(acc[i][j][r] + bv4[j]);
        }
    }
}

// ---------------------------------------------------------------------------
// vtransc: Vtc[b][d][j] = Vhc[b][j][d]  (straight transpose, compacted rows)
// ---------------------------------------------------------------------------
__global__ __launch_bounds__(256) void vtransc_kernel(
    const u16* __restrict__ Vhc, const int* __restrict__ cnts,
    u16* __restrict__ Vtc)
{
    __shared__ u16 tile[64][72];
    const int b = blockIdx.z;
    const int l0 = blockIdx.y * 64, d0 = blockIdx.x * 64;
    if (l0 >= rup(cnts[b * 2], 64)) return;
    const int t = threadIdx.x;
    const int r = t >> 2, cq = (t & 3) * 16;

    const u16* src = Vhc + (size_t)(b * Ln + l0 + r) * Dn + d0 + cq;
    *(uint4*)&tile[r][cq]     = *(const uint4*)(src);
    *(uint4*)&tile[r][cq + 8] = *(const uint4*)(src + 8);
    __syncthreads();

    u16 tmp[16];
    #pragma unroll
    for (int i = 0; i < 16; ++i) tmp[i] = tile[cq + i][r];
    u16* dst = Vtc + (size_t)b * Dn * Ln + (size_t)(d0 + r) * Ln + l0 + cq;
    *(uint4*)(dst)     = *(uint4*)&tmp[0];
    *(uint4*)(dst + 8) = *(uint4*)&tmp[8];
}

// ---------------------------------------------------------------------------
// scorec: Ec[b,q,j] = bf16( Xq[b,q,:].Gt[b,j,:] + u[b,q] + vc[b,j] )
// for compacted j < kc; pad cols get bf16(MASKED). All-linear staging.
// XCD-chunked 1D grid (2048).
// ---------------------------------------------------------------------------
__global__ __launch_bounds__(256) void scorec_kernel(
    const u16* __restrict__ Xq, const u16* __restrict__ Gt,
    const int* __restrict__ cnts,
    const float* __restrict__ u, const float* __restrict__ vc,
    u16* __restrict__ Ec)
{
    __shared__ __align__(16) unsigned char As[128 * 128];
    __shared__ __align__(16) unsigned char Bs[128 * 128];

    // swizzle: nwg = 2048 = 8 * 256
    const int d = blockIdx.x;
    const int f = (d & 7) * 256 + (d >> 3);
    const int b = f >> 8;
    const int rem = f & 255;
    const int m0 = (rem >> 4) * 128;  // 16 q-tiles
    const int n0 = (rem & 15) * 128;  // 16 k-tiles

    const int kc_b = cnts[b * 2];
    if (n0 >= kc_b) return;
    const int tid = threadIdx.x, lane = tid & 63, wid = tid >> 6;
    const int wm = (wid >> 1) * 64, wn = (wid & 1) * 64;

    const size_t boff = (size_t)b * Ln * Dn;
    const u16* Xq_b = Xq + boff;
    const u16* Gt_b = Gt + boff;

    const u16* gA[4]; const u16* gB[4]; int ldsOff[4];
    #pragma unroll
    for (int q = 0; q < 4; ++q) {
        int c = wid * 4 + q;
        int row = c * 8 + (lane >> 3);
        int sig = (lane & 7) ^ (row & 7);
        gA[q] = Xq_b + (size_t)(m0 + row) * Dn + sig * 8;
        gB[q] = Gt_b + (size_t)(n0 + row) * Dn + sig * 8;
        ldsOff[q] = c * 1024;
    }

    f32x4 acc[4][4];
    const f32x4 z4 = {0.f, 0.f, 0.f, 0.f};
    #pragma unroll
    for (int i = 0; i < 4; ++i)
        #pragma unroll
        for (int j = 0; j < 4; ++j) acc[i][j] = z4;

    for (int k0 = 0; k0 < Dn; k0 += 64) {
        #pragma unroll
        for (int q = 0; q < 4; ++q) {
            gload16(gA[q], As + ldsOff[q]);
            gload16(gB[q], Bs + ldsOff[q]);
            gA[q] += 64; gB[q] += 64;
        }
        __syncthreads();

        const int sh = lane >> 4;
        #pragma unroll
        for (int s = 0; s < 2; ++s) {
            bf16x8 af[4], bf[4];
            #pragma unroll
            for (int i = 0; i < 4; ++i) {
                int row = wm + i * 16 + (lane & 15);
                af[i] = *(const bf16x8*)(As + row * 128 + (((s * 4 + sh) ^ (row & 7)) << 4));
            }
            #pragma unroll
            for (int j = 0; j < 4; ++j) {
                int row = wn + j * 16 + (lane & 15);
                bf[j] = *(const bf16x8*)(Bs + row * 128 + (((s * 4 + sh) ^ (row & 7)) << 4));
            }
            #pragma unroll
            for (int i = 0; i < 4; ++i)
                #pragma unroll
                for (int j = 0; j < 4; ++j)
                    acc[i][j] = MFMA16(af[i], bf[j], acc[i][j]);
        }
        __syncthreads();
    }

    float vcl[4];
    #pragma unroll
    for (int j = 0; j < 4; ++j) vcl[j] = vc[b * Ln + n0 + wn + j * 16 + (lane & 15)];
    #pragma unroll
    for (int i = 0; i < 4; ++i) {
        #pragma unroll
        for (int r = 0; r < 4; ++r) {
            int m = m0 + wm + i * 16 + (lane >> 4) * 4 + r;
            float um = u[b * Ln + m];
            u16* orow = Ec + ((size_t)(b * Ln + m)) * Ln + n0 + wn;
            #pragma unroll
            for (int j = 0; j < 4; ++j) {
                int jj = n0 + wn + j * 16 + (lane & 15);
                orow[j * 16 + (lane & 15)] =
                    f2bf((jj < kc_b) ? (acc[i][j][r] + um + vcl[j]) : MASKED_VAL);
            }
        }
    }
}

// ---------------------------------------------------------------------------
// stats_expand: one block per (b,q) row.
// If q-unmasked: block-reduce max/sum, write bf16 P row (q-compacted layout).
// Else: zero the out_a row (replaces zeroa kernel).
// Always: expand bf16 Ec row -> full masked f32 e row (kpos gather).
// ---------------------------------------------------------------------------
__global__ __launch_bounds__(256) void stats_expand_kernel(
    const u16* __restrict__ Ec, const int* __restrict__ kpos,
    const int* __restrict__ qpos, const int* __restrict__ cnts,
    u16* __restrict__ Pc, float* __restrict__ e, float* __restrict__ out_a)
{
    __shared__ float redm[4];
    __shared__ float reds[4];
    const int row = blockIdx.x;
    const int b = row >> 11;
    const int t = threadIdx.x;
    const u16* er = Ec + (size_t)row * Ln;
    const int qp = qpos[row];

    if (qp >= 0) {
        const int bound = rup(cnts[b * 2], 64);
        const int lane = t & 63, wave = t >> 6;
        float v[8];
        int base = t * 8;
        if (base < bound) {
            uint4 x = *(const uint4*)(er + base);
            const u16* xs = (const u16*)&x;
            #pragma unroll
            for (int j = 0; j < 8; ++j) v[j] = bf2f(xs[j]);
        } else {
            #pragma unroll
            for (int j = 0; j < 8; ++j) v[j] = MASKED_VAL;
        }

        float mx = v[0];
        #pragma unroll
        for (int j = 1; j < 8; ++j) mx = fmaxf(mx, v[j]);
        #pragma unroll
        for (int o = 32; o > 0; o >>= 1) mx = fmaxf(mx, __shfl_xor(mx, o, 64));
        if (lane == 0) redm[wave] = mx;
        __syncthreads();
        mx = fmaxf(fmaxf(redm[0], redm[1]), fmaxf(redm[2], redm[3]));

        float s = 0.f;
        #pragma unroll
        for (int j = 0; j < 8; ++j) s += __expf(v[j] - mx);
        #pragma unroll
        for (int o = 32; o > 0; o >>= 1) s += __shfl_xor(s, o, 64);
        if (lane == 0) reds[wave] = s;
        __syncthreads();
        s = reds[0] + reds[1] + reds[2] + reds[3];
        float sinv = 1.0f / s;

        u32 P[4];
        #pragma unroll
        for (int j = 0; j < 4; ++j)
            P[j] = pack2(__expf(v[2*j] - mx) * sinv, __expf(v[2*j+1] - mx) * sinv);
        u16* pr = Pc + ((size_t)b * Ln + qp) * Ln + t * 8;
        *(uint4*)pr = make_uint4(P[0], P[1], P[2], P[3]);
    } else {
        *(float4*)(out_a + (size_t)row * Dn + t * 4) = make_float4(0.f, 0.f, 0.f, 0.f);
    }

    // expansion (reads Ec, writes e; independent of P path)
    const int* kp = kpos + b * Ln;
    const int k = t * 8;
    int p[8];
    *(int4*)&p[0] = *(const int4*)(kp + k);
    *(int4*)&p[4] = *(const int4*)(kp + k + 4);
    float o[8];
    #pragma unroll
    for (int j = 0; j < 8; ++j)
        o[j] = (p[j] >= 0) ? bf2f(er[p[j]]) : MASKED_VAL;

    float* eo = e + (size_t)row * Ln + k;
    *(float4*)(eo)     = make_float4(o[0], o[1], o[2], o[3]);
    *(float4*)(eo + 4) = make_float4(o[4], o[5], o[6], o[7]);
}

// ---------------------------------------------------------------------------
// pvc: a[qidx[i], :] = Pc[b,i,:] @ Vtc^T over compacted k. Pure GEMM.
// XCD-chunked grid (1024).
// ---------------------------------------------------------------------------
__global__ __launch_bounds__(256) void pvc_kernel(
    const u16* __restrict__ Pc, const u16* __restrict__ Vtc,
    const int* __restrict__ qidx, const int* __restrict__ cnts,
    float* __restrict__ out_a)
{
    __shared__ __align__(16) unsigned char As[128 * 128];
    __shared__ __align__(16) unsigned char Bs[128 * 128];

    // swizzle: nwg = 1024 = 8 * 128
    const int d = blockIdx.x;
    const int f = (d & 7) * 128 + (d >> 3);
    const int b = f >> 7;
    const int rem = f & 127;
    const int m0 = (rem >> 3) * 128;  // 16 compacted q tiles
    const int n0 = (rem & 7) * 128;   // 8 d tiles

    const int kc_b = cnts[b * 2], qc_b = cnts[b * 2 + 1];
    if (m0 >= rup(qc_b, 128)) return;
    const int kbound = rup(kc_b, 64);
    const int tid = threadIdx.x, lane = tid & 63, wid = tid >> 6;
    const int wm = (wid >> 1) * 64, wn = (wid & 1) * 64;

    const u16* Pc_b  = Pc  + (size_t)b * Ln * Ln;
    const u16* Vtc_b = Vtc + (size_t)b * Dn * Ln;
    const int* qidx_b = qidx + b * Ln;

    const u16* gA[4]; const u16* gB[4]; int ldsOff[4];
    #pragma unroll
    for (int q = 0; q < 4; ++q) {
        int c = wid * 4 + q;
        int row = c * 8 + (lane >> 3);
        int sig = (lane & 7) ^ (row & 7);
        gA[q] = Pc_b  + (size_t)(m0 + row) * Ln + sig * 8;
        gB[q] = Vtc_b + (size_t)(n0 + row) * Ln + sig * 8;
        ldsOff[q] = c * 1024;
    }

    f32x4 acc[4][4];
    const f32x4 z4 = {0.f, 0.f, 0.f, 0.f};
    #pragma unroll
    for (int i = 0; i < 4; ++i)
        #pragma unroll
        for (int j = 0; j < 4; ++j) acc[i][j] = z4;

    for (int k0 = 0; k0 < kbound; k0 += 64) {
        #pragma unroll
        for (int q = 0; q < 4; ++q) {
            gload16(gA[q], As + ldsOff[q]);
            gload16(gB[q], Bs + ldsOff[q]);
            gA[q] += 64; gB[q] += 64;
        }
        __syncthreads();

        const int sh = lane >> 4;
        #pragma unroll
        for (int s = 0; s < 2; ++s) {
            bf16x8 af[4], bv[4];
            #pragma unroll
            for (int i = 0; i < 4; ++i) {
                int row = wm + i * 16 + (lane & 15);
                af[i] = *(const bf16x8*)(As + row * 128 + (((s * 4 + sh) ^ (row & 7)) << 4));
            }
            #pragma unroll
            for (int j = 0; j < 4; ++j) {
                int row = wn + j * 16 + (lane & 15);
                bv[j] = *(const bf16x8*)(Bs + row * 128 + (((s * 4 + sh) ^ (row & 7)) << 4));
            }
            #pragma unroll
            for (int i = 0; i < 4; ++i)
                #pragma unroll
                for (int j = 0; j < 4; ++j)
                    acc[i][j] = MFMA16(af[i], bv[j], acc[i][j]);
        }
        __syncthreads();
    }

    #pragma unroll
    for (int i = 0; i < 4; ++i) {
        #pragma unroll
        for (int r = 0; r < 4; ++r) {
            int gi = m0 + wm + i * 16 + (lane >> 4) * 4 + r;
            if (gi < qc_b) {
                int gm = qidx_b[gi];
                float* orow = out_a + (size_t)(b * Ln + gm) * Dn + n0 + wn;
                #pragma unroll
                for (int j = 0; j < 4; ++j)
                    orow[j * 16 + (lane & 15)] = acc[i][j][r];
            }
        }
    }
}

// ---------------------------------------------------------------------------
extern "C" void kernel_launch(void* const* d_in, const int* in_sizes, int n_in,
                              void* d_out, int out_size, void* d_ws, size_t ws_size,
                              hipStream_t stream)
{
    const float* Q  = (const float*)d_in[0];
    const float* K  = (const float*)d_in[1];
    const float* V  = (const float*)d_in[2];
    const float* Wq = (const float*)d_in[3];
    const float* bq = (const float*)d_in[4];
    const float* Wk = (const float*)d_in[5];
    const float* bk = (const float*)d_in[6];
    const float* Wv = (const float*)d_in[7];
    const float* bv = (const float*)d_in[8];
    const int* q_mask = (const int*)d_in[9];
    const int* k_mask = (const int*)d_in[10];

    float* out_a = (float*)d_out;                       // [B, L, D]
    float* out_e = out_a + (size_t)Bn * Ln * Dn;        // [B, L, L]

    const size_t NE = (size_t)Bn * Ln * Dn;             // 16,777,216
    const size_t NW = (size_t)Dn * Dn;                  // 1,048,576
    const int BL = Bn * Ln;                             // 16,384

    // ws layout (aliasing plan):
    //   [Vc, Xkc]  -> aliased by Ec (bf16 e', 2*NE) after both are dead
    //   [Gt, Vhc]  -> aliased by Pc (bf16 P,  2*NE) after both are dead
    //   Xq, Vtc, Wvb, Wqt, Wkt, Mb, small tables
    u16* Vc  = (u16*)d_ws;
    u16* Xkc = Vc + NE;
    u16* Gt  = Xkc + NE;
    u16* Vhc = Gt + NE;
    u16* Xq  = Vhc + NE;
    u16* Vtc = Xq + NE;
    u16* Wvb = Vtc + NE;
    u16* Wqt = Wvb + NW;
    u16* Wkt = Wqt + NW;
    u16* Mb  = Wkt + NW;
    float* w1    = (float*)(Mb + NW);
    float* w2    = w1 + Dn;
    float* cbuf  = w2 + Dn;
    float* uarr  = cbuf + 4;
    float* vc    = uarr + BL;
    int* kidx = (int*)(vc + BL);
    int* kpos = kidx + BL;
    int* qidx = kpos + BL;
    int* qpos = qidx + BL;
    int* cnts = qpos + BL;

    u16* Ec = Vc;   // [B][L][L] bf16, aliases Vc+Xkc (dead after projv/gt)
    u16* Pc = Gt;   // [B][L][L] bf16 (q-compacted rows), aliases Gt+Vhc

    dim3 blk(256);

    // 0) mask compaction tables
    prep_kernel<<<dim3(Bn), blk, 0, stream>>>(k_mask, q_mask, kidx, kpos, qidx, qpos, cnts);

    // 1) fused weight prep: Wqt/Wkt transpose, Wvb convert, w1/w2, c
    wprep_kernel<<<dim3(1033), blk, 0, stream>>>(
        Wq, Wk, Wv, bq, bk, Wqt, Wkt, Wvb, w1, w2, cbuf);

    // 2) convert Q + fused u-dot; convert gathered K/V + fused vc-dot
    convq_kernel<<<dim3(BL), blk, 0, stream>>>(Q, w1, cbuf, Xq, uarr);
    convkv_kernel<<<dim3(Ln, 2, Bn), blk, 0, stream>>>(
        K, V, kidx, cnts, w2, Xkc, Vc, vc);

    // 3) Mb = Wq^T Wk (row-major M), bf16
    mgemm_kernel<<<dim3(8, 8), blk, 0, stream>>>(Wqt, Wkt, Mb);

    // 4) Gt[b] = Xkc[b] @ M^T (compacted rows); Vhc = Vc @ Wv^T + bv
    gt_kernel<<<dim3(Dn / 128, Ln / 128, Bn), blk, 0, stream>>>(Xkc, Mb, cnts, Gt);
    projv_kernel<<<dim3(Dn / 128, Ln / 128, Bn), blk, 0, stream>>>(
        Vc, Wvb, bv, cnts, Vhc);

    // 5) straight transpose of compacted V
    vtransc_kernel<<<dim3(Dn / 64, Ln / 64, Bn), blk, 0, stream>>>(Vhc, cnts, Vtc);

    // 6) compacted scores (Xq . Gt + u + vc) -> bf16 Ec (overwrites Vc/Xkc)
    scorec_kernel<<<dim3(2048), blk, 0, stream>>>(Xq, Gt, cnts, uarr, vc, Ec);

    // 7) fused stats + bf16 P emission + e expand + masked-q a zeroing
    stats_expand_kernel<<<dim3(BL), blk, 0, stream>>>(
        Ec, kpos, qpos, cnts, Pc, out_e, out_a);

    // 8) pure-GEMM PV
    pvc_kernel<<<dim3(1024), blk, 0, stream>>>(Pc, Vtc, qidx, cnts, out_a);
}

// Round 13
// 338.872 us; speedup vs baseline: 1.0842x; 1.0842x over previous
//
#include <hip/hip_runtime.h>
#include <cstddef>
#include <cstdint>

constexpr int Bn = 8;
constexpr int Ln = 2048;
constexpr int Dn = 1024;
constexpr float MASKED_VAL = -2147483648.0f;  // -2^31

typedef unsigned short u16;
typedef unsigned int   u32;
typedef __attribute__((ext_vector_type(8))) __bf16 bf16x8;
typedef __attribute__((ext_vector_type(4))) float  f32x4;

__device__ __forceinline__ u16 f2bf(float x) {
    u32 u = __float_as_uint(x);
    u += 0x7FFFu + ((u >> 16) & 1u);
    return (u16)(u >> 16);
}
__device__ __forceinline__ float bf2f(u16 h) {
    return __uint_as_float(((u32)h) << 16);
}
__device__ __forceinline__ u32 pack2(float a, float b) {
    return (u32)f2bf(a) | ((u32)f2bf(b) << 16);
}
__device__ __forceinline__ int rup(int x, int m) { return (x + m - 1) & ~(m - 1); }

__device__ __forceinline__ void gload16(const void* g, void* l) {
    typedef const __attribute__((address_space(1))) unsigned int* gp_t;
    typedef __attribute__((address_space(3))) unsigned int* lp_t;
    __builtin_amdgcn_global_load_lds((gp_t)g, (lp_t)l, 16, 0, 0);
}

#define MFMA16(a, b, c) __builtin_amdgcn_mfma_f32_16x16x32_bf16((a), (b), (c), 0, 0, 0)

// ---------------------------------------------------------------------------
// prep: per batch, compaction tables. kidx (padded w/ last valid), kpos
// (-1 if masked), qidx (padded w/ 0), qpos (-1 if masked), counts.
// ---------------------------------------------------------------------------
__global__ __launch_bounds__(256) void prep_kernel(
    const int* __restrict__ k_mask, const int* __restrict__ q_mask,
    int* __restrict__ kidx, int* __restrict__ kpos,
    int* __restrict__ qidx, int* __restrict__ qpos, int* __restrict__ cnts)
{
    __shared__ int sc[256];
    __shared__ int lastv;
    const int b = blockIdx.x, t = threadIdx.x;
    for (int pass = 0; pass < 2; ++pass) {
        const int* msk = (pass ? q_mask : k_mask) + b * Ln;
        int* idx = (pass ? qidx : kidx) + b * Ln;
        int* pos = (pass ? qpos : kpos) + b * Ln;
        int f[8], s = 0;
        #pragma unroll
        for (int j = 0; j < 8; ++j) { f[j] = (msk[t * 8 + j] != 0) ? 1 : 0; s += f[j]; }
        sc[t] = s;
        __syncthreads();
        #pragma unroll
        for (int o = 1; o < 256; o <<= 1) {
            int v = (t >= o) ? sc[t - o] : 0;
            __syncthreads();
            sc[t] += v;
            __syncthreads();
        }
        int incl = sc[t];
        int total = sc[255];
        int p = incl - s;
        #pragma unroll
        for (int j = 0; j < 8; ++j) {
            pos[t * 8 + j] = f[j] ? p : -1;
            if (f[j]) { idx[p] = t * 8 + j; ++p; }
        }
        __syncthreads();
        if (t == 0) {
            cnts[b * 2 + pass] = total;
            lastv = (total > 0) ? idx[total - 1] : 0;
        }
        __syncthreads();
        int padv = (pass == 0) ? lastv : 0;
        for (int e2 = total + t; e2 < Ln; e2 += 256) idx[e2] = padv;
        __syncthreads();
    }
}

// ---------------------------------------------------------------------------
// wprep: fused weight prep (streaming-clean parts only).
//   blocks [0,512):    wtrans Wq/Wk fp32 -> Wqt/Wkt bf16 [d][e]
//   blocks [512,1024): convert Wv -> Wvb bf16
//   block 1024:        cbuf[0] = bq.bk
// (w1/w2 moved back to coalesced wvec kernel -- fp32 column loop was a
//  latency-bound ~35us tail in R12.)
// ---------------------------------------------------------------------------
__global__ __launch_bounds__(256) void wprep_kernel(
    const float* __restrict__ Wq, const float* __restrict__ Wk, const float* __restrict__ Wv,
    const float* __restrict__ bq, const float* __restrict__ bk,
    u16* __restrict__ Wqt, u16* __restrict__ Wkt, u16* __restrict__ Wvb,
    float* __restrict__ cbuf)
{
    __shared__ float tile[64][68];
    const int blk = blockIdx.x;
    const int t = threadIdx.x;

    if (blk < 512) {
        const float* src = (blk >= 256) ? Wk : Wq;
        u16* dst = (blk >= 256) ? Wkt : Wqt;
        const int rem = blk & 255;
        const int e0 = (rem >> 4) * 64, d0 = (rem & 15) * 64;
        const int r = t >> 2, cq = (t & 3) * 16;
        const float* s = src + (size_t)(e0 + r) * Dn + d0 + cq;
        #pragma unroll
        for (int i = 0; i < 4; ++i)
            *(float4*)&tile[r][cq + i * 4] = *(const float4*)(s + i * 4);
        __syncthreads();
        u32 o[8];
        #pragma unroll
        for (int i = 0; i < 8; ++i)
            o[i] = pack2(tile[cq + 2 * i][r], tile[cq + 2 * i + 1][r]);
        u16* d = dst + (size_t)(d0 + r) * Dn + e0 + cq;
        *(uint4*)(d)     = make_uint4(o[0], o[1], o[2], o[3]);
        *(uint4*)(d + 8) = make_uint4(o[4], o[5], o[6], o[7]);
    } else if (blk < 1024) {
        int i = ((blk - 512) * 256 + t) * 8;
        float f[8];
        *(float4*)&f[0] = *(const float4*)(Wv + i);
        *(float4*)&f[4] = *(const float4*)(Wv + i + 4);
        u32 H[4];
        #pragma unroll
        for (int j = 0; j < 4; ++j) H[j] = pack2(f[2*j], f[2*j+1]);
        *(uint4*)(Wvb + i) = make_uint4(H[0], H[1], H[2], H[3]);
    } else {
        if (t < 64) {
            float s = 0.f;
            #pragma unroll
            for (int i = 0; i < 16; ++i) s += bq[t + 64 * i] * bk[t + 64 * i];
            #pragma unroll
            for (int o = 32; o; o >>= 1) s += __shfl_xor(s, o, 64);
            if (t == 0) cbuf[0] = s;
        }
    }
}

// ---------------------------------------------------------------------------
// wvec: w1[d] = Wqt[d,:].bk ; w2[d] = Wkt[d,:].bq   (one wave per d,
// coalesced bf16 row reads -- the R11 fast form).
// ---------------------------------------------------------------------------
__global__ __launch_bounds__(256) void wvec_kernel(
    const u16* __restrict__ Wqt, const u16* __restrict__ Wkt,
    const float* __restrict__ bk, const float* __restrict__ bq,
    float* __restrict__ w1, float* __restrict__ w2)
{
    const int y = blockIdx.y;
    const u16* src = y ? Wkt : Wqt;
    const float* vec = y ? bq : bk;
    float* out = y ? w2 : w1;
    const int d = blockIdx.x * 4 + (threadIdx.x >> 6);
    const int l = threadIdx.x & 63;
    float s = 0.f;
    #pragma unroll
    for (int i = 0; i < 16; ++i) {
        int e = l + 64 * i;
        s += bf2f(src[(size_t)d * Dn + e]) * vec[e];
    }
    #pragma unroll
    for (int o = 32; o; o >>= 1) s += __shfl_xor(s, o, 64);
    if (l == 0) out[d] = s;
}

// ---------------------------------------------------------------------------
// convq: one block per (b,l) row. Converts Q row -> Xq bf16 AND computes
// u[row] = bf16(Q[row,:]).w1 + c  (block reduce) in the same pass.
// ---------------------------------------------------------------------------
__global__ __launch_bounds__(256) void convq_kernel(
    const float* __restrict__ Q, const float* __restrict__ w1,
    const float* __restrict__ cbuf, u16* __restrict__ Xq, float* __restrict__ u)
{
    __shared__ float red[4];
    const int row = blockIdx.x;
    const int t = threadIdx.x;
    float4 f = *(const float4*)(Q + (size_t)row * Dn + t * 4);
    u32 p0 = pack2(f.x, f.y), p1 = pack2(f.z, f.w);
    *(uint2*)(Xq + (size_t)row * Dn + t * 4) = make_uint2(p0, p1);

    float4 w = *(const float4*)(w1 + t * 4);
    float s = bf2f((u16)(p0 & 0xFFFFu)) * w.x + bf2f((u16)(p0 >> 16)) * w.y
            + bf2f((u16)(p1 & 0xFFFFu)) * w.z + bf2f((u16)(p1 >> 16)) * w.w;
    #pragma unroll
    for (int o = 32; o; o >>= 1) s += __shfl_xor(s, o, 64);
    if ((t & 63) == 0) red[t >> 6] = s;
    __syncthreads();
    if (t == 0) u[row] = red[0] + red[1] + red[2] + red[3] + cbuf[0];
}

// ---------------------------------------------------------------------------
// convkv: one block per (compacted row j, y, b). y=0: K -> Xkc (+ vc dot
// with w2); y=1: V -> Vc. Only rows j < rup(kc,128).
// ---------------------------------------------------------------------------
__global__ __launch_bounds__(256) void convkv_kernel(
    const float* __restrict__ K, const float* __restrict__ V,
    const int* __restrict__ kidx, const int* __restrict__ cnts,
    const float* __restrict__ w2, u16* __restrict__ Xkc, u16* __restrict__ Vc,
    float* __restrict__ vc)
{
    __shared__ float red[4];
    const int b = blockIdx.z, j = blockIdx.x, y = blockIdx.y;
    if (j >= rup(cnts[b * 2], 128)) return;
    const int srow = kidx[b * Ln + j];
    const int t = threadIdx.x;
    float4 f = *(const float4*)((y ? V : K) + ((size_t)b * Ln + srow) * Dn + t * 4);
    u32 p0 = pack2(f.x, f.y), p1 = pack2(f.z, f.w);
    *(uint2*)((y ? Vc : Xkc) + ((size_t)b * Ln + j) * Dn + t * 4) = make_uint2(p0, p1);

    if (y == 0) {
        float4 w = *(const float4*)(w2 + t * 4);
        float s = bf2f((u16)(p0 & 0xFFFFu)) * w.x + bf2f((u16)(p0 >> 16)) * w.y
                + bf2f((u16)(p1 & 0xFFFFu)) * w.z + bf2f((u16)(p1 >> 16)) * w.w;
        #pragma unroll
        for (int o = 32; o; o >>= 1) s += __shfl_xor(s, o, 64);
        if ((t & 63) == 0) red[t >> 6] = s;
        __syncthreads();
        if (t == 0) vc[b * Ln + j] = red[0] + red[1] + red[2] + red[3];
    }
}

// ---------------------------------------------------------------------------
// mgemm: C[m][n] = sum_e A[m,e] * B[n,e]  (1024x1024x1024, bf16 out).
// Called with (Wqt, Wkt) -> Mb[m][n] = (Wq^T Wk)[m][n]  (row-major M).
// ---------------------------------------------------------------------------
__global__ __launch_bounds__(256) void mgemm_kernel(
    const u16* __restrict__ A, const u16* __restrict__ B, u16* __restrict__ C)
{
    __shared__ __align__(16) unsigned char As[128 * 128];
    __shared__ __align__(16) unsigned char Bs[128 * 128];

    const int m0 = blockIdx.y * 128, n0 = blockIdx.x * 128;
    const int tid = threadIdx.x, lane = tid & 63, wid = tid >> 6;
    const int wm = (wid >> 1) * 64, wn = (wid & 1) * 64;

    const u16* gA[4]; const u16* gB[4]; int ldsOff[4];
    #pragma unroll
    for (int q = 0; q < 4; ++q) {
        int c = wid * 4 + q;
        int row = c * 8 + (lane >> 3);
        int sig = (lane & 7) ^ (row & 7);
        gA[q] = A + (size_t)(m0 + row) * Dn + sig * 8;
        gB[q] = B + (size_t)(n0 + row) * Dn + sig * 8;
        ldsOff[q] = c * 1024;
    }

    f32x4 acc[4][4];
    const f32x4 z4 = {0.f, 0.f, 0.f, 0.f};
    #pragma unroll
    for (int i = 0; i < 4; ++i)
        #pragma unroll
        for (int j = 0; j < 4; ++j) acc[i][j] = z4;

    for (int k0 = 0; k0 < Dn; k0 += 64) {
        #pragma unroll
        for (int q = 0; q < 4; ++q) {
            gload16(gA[q], As + ldsOff[q]);
            gload16(gB[q], Bs + ldsOff[q]);
            gA[q] += 64; gB[q] += 64;
        }
        __syncthreads();

        const int sh = lane >> 4;
        #pragma unroll
        for (int s = 0; s < 2; ++s) {
            bf16x8 af[4], bf[4];
            #pragma unroll
            for (int i = 0; i < 4; ++i) {
                int row = wm + i * 16 + (lane & 15);
                af[i] = *(const bf16x8*)(As + row * 128 + (((s * 4 + sh) ^ (row & 7)) << 4));
            }
            #pragma unroll
            for (int j = 0; j < 4; ++j) {
                int row = wn + j * 16 + (lane & 15);
                bf[j] = *(const bf16x8*)(Bs + row * 128 + (((s * 4 + sh) ^ (row & 7)) << 4));
            }
            #pragma unroll
            for (int i = 0; i < 4; ++i)
                #pragma unroll
                for (int j = 0; j < 4; ++j)
                    acc[i][j] = MFMA16(af[i], bf[j], acc[i][j]);
        }
        __syncthreads();
    }

    #pragma unroll
    for (int i = 0; i < 4; ++i) {
        #pragma unroll
        for (int r = 0; r < 4; ++r) {
            int m = m0 + wm + i * 16 + (lane >> 4) * 4 + r;
            u16* oh = C + (size_t)m * Dn + n0 + wn;
            #pragma unroll
            for (int j = 0; j < 4; ++j)
                oh[j * 16 + (lane & 15)] = f2bf(acc[i][j][r]);
        }
    }
}

// ---------------------------------------------------------------------------
// gt: Gt[b][j][:] = Xkc[b][j][:] @ Mb^T  (compacted rows only, no bias)
// ---------------------------------------------------------------------------
__global__ __launch_bounds__(256) void gt_kernel(
    const u16* __restrict__ Xkc, const u16* __restrict__ Mb,
    const int* __restrict__ cnts, u16* __restrict__ Gt)
{
    __shared__ __align__(16) unsigned char As[128 * 128];
    __shared__ __align__(16) unsigned char Bs[128 * 128];

    const int b = blockIdx.z;
    const int kc_b = cnts[b * 2];
    const int m0 = blockIdx.y * 128;
    if (m0 >= rup(kc_b, 128)) return;
    const int n0 = blockIdx.x * 128;
    const int tid = threadIdx.x, lane = tid & 63, wid = tid >> 6;
    const int wm = (wid >> 1) * 64, wn = (wid & 1) * 64;

    const u16* Xkc_b = Xkc + (size_t)b * Ln * Dn;

    const u16* gA[4]; const u16* gB[4]; int ldsOff[4];
    #pragma unroll
    for (int q = 0; q < 4; ++q) {
        int c = wid * 4 + q;
        int row = c * 8 + (lane >> 3);
        int sig = (lane & 7) ^ (row & 7);
        gA[q] = Xkc_b + (size_t)(m0 + row) * Dn + sig * 8;
        gB[q] = Mb + (size_t)(n0 + row) * Dn + sig * 8;
        ldsOff[q] = c * 1024;
    }

    f32x4 acc[4][4];
    const f32x4 z4 = {0.f, 0.f, 0.f, 0.f};
    #pragma unroll
    for (int i = 0; i < 4; ++i)
        #pragma unroll
        for (int j = 0; j < 4; ++j) acc[i][j] = z4;

    for (int k0 = 0; k0 < Dn; k0 += 64) {
        #pragma unroll
        for (int q = 0; q < 4; ++q) {
            gload16(gA[q], As + ldsOff[q]);
            gload16(gB[q], Bs + ldsOff[q]);
            gA[q] += 64; gB[q] += 64;
        }
        __syncthreads();

        const int sh = lane >> 4;
        #pragma unroll
        for (int s = 0; s < 2; ++s) {
            bf16x8 af[4], bf[4];
            #pragma unroll
            for (int i = 0; i < 4; ++i) {
                int row = wm + i * 16 + (lane & 15);
                af[i] = *(const bf16x8*)(As + row * 128 + (((s * 4 + sh) ^ (row & 7)) << 4));
            }
            #pragma unroll
            for (int j = 0; j < 4; ++j) {
                int row = wn + j * 16 + (lane & 15);
                bf[j] = *(const bf16x8*)(Bs + row * 128 + (((s * 4 + sh) ^ (row & 7)) << 4));
            }
            #pragma unroll
            for (int i = 0; i < 4; ++i)
                #pragma unroll
                for (int j = 0; j < 4; ++j)
                    acc[i][j] = MFMA16(af[i], bf[j], acc[i][j]);
        }
        __syncthreads();
    }

    u16* Gt_b = Gt + (size_t)b * Ln * Dn;
    #pragma unroll
    for (int i = 0; i < 4; ++i) {
        #pragma unroll
        for (int r = 0; r < 4; ++r) {
            int m = m0 + wm + i * 16 + (lane >> 4) * 4 + r;
            u16* oh = Gt_b + (size_t)m * Dn + n0 + wn;
            #pragma unroll
            for (int j = 0; j < 4; ++j)
                oh[j * 16 + (lane & 15)] = f2bf(acc[i][j][r]);
        }
    }
}

// ---------------------------------------------------------------------------
// projv: Vhc[b][j][:] = Vc[b][j][:] @ Wvb^T + bv (compacted rows, linear A).
// ---------------------------------------------------------------------------
__global__ __launch_bounds__(256) void projv_kernel(
    const u16* __restrict__ Vc, const u16* __restrict__ Wvb,
    const float* __restrict__ bv, const int* __restrict__ cnts,
    u16* __restrict__ Vhc)
{
    __shared__ __align__(16) unsigned char As[128 * 128];
    __shared__ __align__(16) unsigned char Bs[128 * 128];

    const int b = blockIdx.z;
    const int kc_b = cnts[b * 2];
    const int m0 = blockIdx.y * 128;
    if (m0 >= rup(kc_b, 128)) return;
    const int n0 = blockIdx.x * 128;
    const int tid = threadIdx.x, lane = tid & 63, wid = tid >> 6;
    const int wm = (wid >> 1) * 64, wn = (wid & 1) * 64;

    const u16* Vc_b = Vc + (size_t)b * Ln * Dn;

    const u16* gA[4]; const u16* gB[4]; int ldsOff[4];
    #pragma unroll
    for (int q = 0; q < 4; ++q) {
        int c = wid * 4 + q;
        int row = c * 8 + (lane >> 3);
        int sig = (lane & 7) ^ (row & 7);
        gA[q] = Vc_b + (size_t)(m0 + row) * Dn + sig * 8;
        gB[q] = Wvb + (size_t)(n0 + row) * Dn + sig * 8;
        ldsOff[q] = c * 1024;
    }

    f32x4 acc[4][4];
    const f32x4 z4 = {0.f, 0.f, 0.f, 0.f};
    #pragma unroll
    for (int i = 0; i < 4; ++i)
        #pragma unroll
        for (int j = 0; j < 4; ++j) acc[i][j] = z4;

    for (int k0 = 0; k0 < Dn; k0 += 64) {
        #pragma unroll
        for (int q = 0; q < 4; ++q) {
            gload16(gA[q], As + ldsOff[q]);
            gload16(gB[q], Bs + ldsOff[q]);
            gA[q] += 64; gB[q] += 64;
        }
        __syncthreads();

        const int sh = lane >> 4;
        #pragma unroll
        for (int s = 0; s < 2; ++s) {
            bf16x8 af[4], bf[4];
            #pragma unroll
            for (int i = 0; i < 4; ++i) {
                int row = wm + i * 16 + (lane & 15);
                af[i] = *(const bf16x8*)(As + row * 128 + (((s * 4 + sh) ^ (row & 7)) << 4));
            }
            #pragma unroll
            for (int j = 0; j < 4; ++j) {
                int row = wn + j * 16 + (lane & 15);
                bf[j] = *(const bf16x8*)(Bs + row * 128 + (((s * 4 + sh) ^ (row & 7)) << 4));
            }
            #pragma unroll
            for (int i = 0; i < 4; ++i)
                #pragma unroll
                for (int j = 0; j < 4; ++j)
                    acc[i][j] = MFMA16(af[i], bf[j], acc[i][j]);
        }
        __syncthreads();
    }

    float bv4[4];
    #pragma unroll
    for (int j = 0; j < 4; ++j) bv4[j] = bv[n0 + wn + j * 16 + (lane & 15)];
    u16* Vhc_b = Vhc + (size_t)b * Ln * Dn;
    #pragma unroll
    for (int i = 0; i < 4; ++i) {
        #pragma unroll
        for (int r = 0; r < 4; ++r) {
            int m = m0 + wm + i * 16 + (lane >> 4) * 4 + r;
            u16* oh = Vhc_b + (size_t)m * Dn + n0 + wn;
            #pragma unroll
            for (int j = 0; j < 4; ++j)
                oh[j * 16 + (lane & 15)] = f2bf(acc[i][j][r] + bv4[j]);
        }
    }
}

// ---------------------------------------------------------------------------
// vtransc: Vtc[b][d][j] = Vhc[b][j][d]  (straight transpose, compacted rows)
// ---------------------------------------------------------------------------
__global__ __launch_bounds__(256) void vtransc_kernel(
    const u16* __restrict__ Vhc, const int* __restrict__ cnts,
    u16* __restrict__ Vtc)
{
    __shared__ u16 tile[64][72];
    const int b = blockIdx.z;
    const int l0 = blockIdx.y * 64, d0 = blockIdx.x * 64;
    if (l0 >= rup(cnts[b * 2], 64)) return;
    const int t = threadIdx.x;
    const int r = t >> 2, cq = (t & 3) * 16;

    const u16* src = Vhc + (size_t)(b * Ln + l0 + r) * Dn + d0 + cq;
    *(uint4*)&tile[r][cq]     = *(const uint4*)(src);
    *(uint4*)&tile[r][cq + 8] = *(const uint4*)(src + 8);
    __syncthreads();

    u16 tmp[16];
    #pragma unroll
    for (int i = 0; i < 16; ++i) tmp[i] = tile[cq + i][r];
    u16* dst = Vtc + (size_t)b * Dn * Ln + (size_t)(d0 + r) * Ln + l0 + cq;
    *(uint4*)(dst)     = *(uint4*)&tmp[0];
    *(uint4*)(dst + 8) = *(uint4*)&tmp[8];
}

// ---------------------------------------------------------------------------
// scorec: Ec[b,q,j] = bf16( Xq[b,q,:].Gt[b,j,:] + u[b,q] + vc[b,j] )
// for compacted j < kc; pad cols get bf16(MASKED). All-linear staging.
// XCD-chunked 1D grid (2048).
// ---------------------------------------------------------------------------
__global__ __launch_bounds__(256) void scorec_kernel(
    const u16* __restrict__ Xq, const u16* __restrict__ Gt,
    const int* __restrict__ cnts,
    const float* __restrict__ u, const float* __restrict__ vc,
    u16* __restrict__ Ec)
{
    __shared__ __align__(16) unsigned char As[128 * 128];
    __shared__ __align__(16) unsigned char Bs[128 * 128];

    // swizzle: nwg = 2048 = 8 * 256
    const int d = blockIdx.x;
    const int f = (d & 7) * 256 + (d >> 3);
    const int b = f >> 8;
    const int rem = f & 255;
    const int m0 = (rem >> 4) * 128;  // 16 q-tiles
    const int n0 = (rem & 15) * 128;  // 16 k-tiles

    const int kc_b = cnts[b * 2];
    if (n0 >= kc_b) return;
    const int tid = threadIdx.x, lane = tid & 63, wid = tid >> 6;
    const int wm = (wid >> 1) * 64, wn = (wid & 1) * 64;

    const size_t boff = (size_t)b * Ln * Dn;
    const u16* Xq_b = Xq + boff;
    const u16* Gt_b = Gt + boff;

    const u16* gA[4]; const u16* gB[4]; int ldsOff[4];
    #pragma unroll
    for (int q = 0; q < 4; ++q) {
        int c = wid * 4 + q;
        int row = c * 8 + (lane >> 3);
        int sig = (lane & 7) ^ (row & 7);
        gA[q] = Xq_b + (size_t)(m0 + row) * Dn + sig * 8;
        gB[q] = Gt_b + (size_t)(n0 + row) * Dn + sig * 8;
        ldsOff[q] = c * 1024;
    }

    f32x4 acc[4][4];
    const f32x4 z4 = {0.f, 0.f, 0.f, 0.f};
    #pragma unroll
    for (int i = 0; i < 4; ++i)
        #pragma unroll
        for (int j = 0; j < 4; ++j) acc[i][j] = z4;

    for (int k0 = 0; k0 < Dn; k0 += 64) {
        #pragma unroll
        for (int q = 0; q < 4; ++q) {
            gload16(gA[q], As + ldsOff[q]);
            gload16(gB[q], Bs + ldsOff[q]);
            gA[q] += 64; gB[q] += 64;
        }
        __syncthreads();

        const int sh = lane >> 4;
        #pragma unroll
        for (int s = 0; s < 2; ++s) {
            bf16x8 af[4], bf[4];
            #pragma unroll
            for (int i = 0; i < 4; ++i) {
                int row = wm + i * 16 + (lane & 15);
                af[i] = *(const bf16x8*)(As + row * 128 + (((s * 4 + sh) ^ (row & 7)) << 4));
            }
            #pragma unroll
            for (int j = 0; j < 4; ++j) {
                int row = wn + j * 16 + (lane & 15);
                bf[j] = *(const bf16x8*)(Bs + row * 128 + (((s * 4 + sh) ^ (row & 7)) << 4));
            }
            #pragma unroll
            for (int i = 0; i < 4; ++i)
                #pragma unroll
                for (int j = 0; j < 4; ++j)
                    acc[i][j] = MFMA16(af[i], bf[j], acc[i][j]);
        }
        __syncthreads();
    }

    float vcl[4];
    #pragma unroll
    for (int j = 0; j < 4; ++j) vcl[j] = vc[b * Ln + n0 + wn + j * 16 + (lane & 15)];
    #pragma unroll
    for (int i = 0; i < 4; ++i) {
        #pragma unroll
        for (int r = 0; r < 4; ++r) {
            int m = m0 + wm + i * 16 + (lane >> 4) * 4 + r;
            float um = u[b * Ln + m];
            u16* orow = Ec + ((size_t)(b * Ln + m)) * Ln + n0 + wn;
            #pragma unroll
            for (int j = 0; j < 4; ++j) {
                int jj = n0 + wn + j * 16 + (lane & 15);
                orow[j * 16 + (lane & 15)] =
                    f2bf((jj < kc_b) ? (acc[i][j][r] + um + vcl[j]) : MASKED_VAL);
            }
        }
    }
}

// ---------------------------------------------------------------------------
// stats_expand: one block per (b,q) row.
// If q-unmasked: block-reduce max/sum, write bf16 P row (q-compacted layout).
// Else: zero the out_a row.
// Always: expand bf16 Ec row -> full masked f32 e row (kpos gather).
// ---------------------------------------------------------------------------
__global__ __launch_bounds__(256) void stats_expand_kernel(
    const u16* __restrict__ Ec, const int* __restrict__ kpos,
    const int* __restrict__ qpos, const int* __restrict__ cnts,
    u16* __restrict__ Pc, float* __restrict__ e, float* __restrict__ out_a)
{
    __shared__ float redm[4];
    __shared__ float reds[4];
    const int row = blockIdx.x;
    const int b = row >> 11;
    const int t = threadIdx.x;
    const u16* er = Ec + (size_t)row * Ln;
    const int qp = qpos[row];

    if (qp >= 0) {
        const int bound = rup(cnts[b * 2], 64);
        const int lane = t & 63, wave = t >> 6;
        float v[8];
        int base = t * 8;
        if (base < bound) {
            uint4 x = *(const uint4*)(er + base);
            const u16* xs = (const u16*)&x;
            #pragma unroll
            for (int j = 0; j < 8; ++j) v[j] = bf2f(xs[j]);
        } else {
            #pragma unroll
            for (int j = 0; j < 8; ++j) v[j] = MASKED_VAL;
        }

        float mx = v[0];
        #pragma unroll
        for (int j = 1; j < 8; ++j) mx = fmaxf(mx, v[j]);
        #pragma unroll
        for (int o = 32; o > 0; o >>= 1) mx = fmaxf(mx, __shfl_xor(mx, o, 64));
        if (lane == 0) redm[wave] = mx;
        __syncthreads();
        mx = fmaxf(fmaxf(redm[0], redm[1]), fmaxf(redm[2], redm[3]));

        float s = 0.f;
        #pragma unroll
        for (int j = 0; j < 8; ++j) s += __expf(v[j] - mx);
        #pragma unroll
        for (int o = 32; o > 0; o >>= 1) s += __shfl_xor(s, o, 64);
        if (lane == 0) reds[wave] = s;
        __syncthreads();
        s = reds[0] + reds[1] + reds[2] + reds[3];
        float sinv = 1.0f / s;

        u32 P[4];
        #pragma unroll
        for (int j = 0; j < 4; ++j)
            P[j] = pack2(__expf(v[2*j] - mx) * sinv, __expf(v[2*j+1] - mx) * sinv);
        u16* pr = Pc + ((size_t)b * Ln + qp) * Ln + t * 8;
        *(uint4*)pr = make_uint4(P[0], P[1], P[2], P[3]);
    } else {
        *(float4*)(out_a + (size_t)row * Dn + t * 4) = make_float4(0.f, 0.f, 0.f, 0.f);
    }

    // expansion (reads Ec, writes e; independent of P path)
    const int* kp = kpos + b * Ln;
    const int k = t * 8;
    int p[8];
    *(int4*)&p[0] = *(const int4*)(kp + k);
    *(int4*)&p[4] = *(const int4*)(kp + k + 4);
    float o[8];
    #pragma unroll
    for (int j = 0; j < 8; ++j)
        o[j] = (p[j] >= 0) ? bf2f(er[p[j]]) : MASKED_VAL;

    float* eo = e + (size_t)row * Ln + k;
    *(float4*)(eo)     = make_float4(o[0], o[1], o[2], o[3]);
    *(float4*)(eo + 4) = make_float4(o[4], o[5], o[6], o[7]);
}

// ---------------------------------------------------------------------------
// pvc: a[qidx[i], :] = Pc[b,i,:] @ Vtc^T over compacted k. Pure GEMM.
// XCD-chunked grid (1024).
// ---------------------------------------------------------------------------
__global__ __launch_bounds__(256) void pvc_kernel(
    const u16* __restrict__ Pc, const u16* __restrict__ Vtc,
    const int* __restrict__ qidx, const int* __restrict__ cnts,
    float* __restrict__ out_a)
{
    __shared__ __align__(16) unsigned char As[128 * 128];
    __shared__ __align__(16) unsigned char Bs[128 * 128];

    // swizzle: nwg = 1024 = 8 * 128
    const int d = blockIdx.x;
    const int f = (d & 7) * 128 + (d >> 3);
    const int b = f >> 7;
    const int rem = f & 127;
    const int m0 = (rem >> 3) * 128;  // 16 compacted q tiles
    const int n0 = (rem & 7) * 128;   // 8 d tiles

    const int kc_b = cnts[b * 2], qc_b = cnts[b * 2 + 1];
    if (m0 >= rup(qc_b, 128)) return;
    const int kbound = rup(kc_b, 64);
    const int tid = threadIdx.x, lane = tid & 63, wid = tid >> 6;
    const int wm = (wid >> 1) * 64, wn = (wid & 1) * 64;

    const u16* Pc_b  = Pc  + (size_t)b * Ln * Ln;
    const u16* Vtc_b = Vtc + (size_t)b * Dn * Ln;
    const int* qidx_b = qidx + b * Ln;

    const u16* gA[4]; const u16* gB[4]; int ldsOff[4];
    #pragma unroll
    for (int q = 0; q < 4; ++q) {
        int c = wid * 4 + q;
        int row = c * 8 + (lane >> 3);
        int sig = (lane & 7) ^ (row & 7);
        gA[q] = Pc_b  + (size_t)(m0 + row) * Ln + sig * 8;
        gB[q] = Vtc_b + (size_t)(n0 + row) * Ln + sig * 8;
        ldsOff[q] = c * 1024;
    }

    f32x4 acc[4][4];
    const f32x4 z4 = {0.f, 0.f, 0.f, 0.f};
    #pragma unroll
    for (int i = 0; i < 4; ++i)
        #pragma unroll
        for (int j = 0; j < 4; ++j) acc[i][j] = z4;

    for (int k0 = 0; k0 < kbound; k0 += 64) {
        #pragma unroll
        for (int q = 0; q < 4; ++q) {
            gload16(gA[q], As + ldsOff[q]);
            gload16(gB[q], Bs + ldsOff[q]);
            gA[q] += 64; gB[q] += 64;
        }
        __syncthreads();

        const int sh = lane >> 4;
        #pragma unroll
        for (int s = 0; s < 2; ++s) {
            bf16x8 af[4], bv[4];
            #pragma unroll
            for (int i = 0; i < 4; ++i) {
                int row = wm + i * 16 + (lane & 15);
                af[i] = *(const bf16x8*)(As + row * 128 + (((s * 4 + sh) ^ (row & 7)) << 4));
            }
            #pragma unroll
            for (int j = 0; j < 4; ++j) {
                int row = wn + j * 16 + (lane & 15);
                bv[j] = *(const bf16x8*)(Bs + row * 128 + (((s * 4 + sh) ^ (row & 7)) << 4));
            }
            #pragma unroll
            for (int i = 0; i < 4; ++i)
                #pragma unroll
                for (int j = 0; j < 4; ++j)
                    acc[i][j] = MFMA16(af[i], bv[j], acc[i][j]);
        }
        __syncthreads();
    }

    #pragma unroll
    for (int i = 0; i < 4; ++i) {
        #pragma unroll
        for (int r = 0; r < 4; ++r) {
            int gi = m0 + wm + i * 16 + (lane >> 4) * 4 + r;
            if (gi < qc_b) {
                int gm = qidx_b[gi];
                float* orow = out_a + (size_t)(b * Ln + gm) * Dn + n0 + wn;
                #pragma unroll
                for (int j = 0; j < 4; ++j)
                    orow[j * 16 + (lane & 15)] = acc[i][j][r];
            }
        }
    }
}

// ---------------------------------------------------------------------------
extern "C" void kernel_launch(void* const* d_in, const int* in_sizes, int n_in,
                              void* d_out, int out_size, void* d_ws, size_t ws_size,
                              hipStream_t stream)
{
    const float* Q  = (const float*)d_in[0];
    const float* K  = (const float*)d_in[1];
    const float* V  = (const float*)d_in[2];
    const float* Wq = (const float*)d_in[3];
    const float* bq = (const float*)d_in[4];
    const float* Wk = (const float*)d_in[5];
    const float* bk = (const float*)d_in[6];
    const float* Wv = (const float*)d_in[7];
    const float* bv = (const float*)d_in[8];
    const int* q_mask = (const int*)d_in[9];
    const int* k_mask = (const int*)d_in[10];

    float* out_a = (float*)d_out;                       // [B, L, D]
    float* out_e = out_a + (size_t)Bn * Ln * Dn;        // [B, L, L]

    const size_t NE = (size_t)Bn * Ln * Dn;             // 16,777,216
    const size_t NW = (size_t)Dn * Dn;                  // 1,048,576
    const int BL = Bn * Ln;                             // 16,384

    // ws layout (aliasing plan):
    //   [Vc, Xkc]  -> aliased by Ec (bf16 e', 2*NE) after both are dead
    //   [Gt, Vhc]  -> aliased by Pc (bf16 P,  2*NE) after both are dead
    //   Xq, Vtc, Wvb, Wqt, Wkt, Mb, small tables
    u16* Vc  = (u16*)d_ws;
    u16* Xkc = Vc + NE;
    u16* Gt  = Xkc + NE;
    u16* Vhc = Gt + NE;
    u16* Xq  = Vhc + NE;
    u16* Vtc = Xq + NE;
    u16* Wvb = Vtc + NE;
    u16* Wqt = Wvb + NW;
    u16* Wkt = Wqt + NW;
    u16* Mb  = Wkt + NW;
    float* w1    = (float*)(Mb + NW);
    float* w2    = w1 + Dn;
    float* cbuf  = w2 + Dn;
    float* uarr  = cbuf + 4;
    float* vc    = uarr + BL;
    int* kidx = (int*)(vc + BL);
    int* kpos = kidx + BL;
    int* qidx = kpos + BL;
    int* qpos = qidx + BL;
    int* cnts = qpos + BL;

    u16* Ec = Vc;   // [B][L][L] bf16, aliases Vc+Xkc (dead after projv/gt)
    u16* Pc = Gt;   // [B][L][L] bf16 (q-compacted rows), aliases Gt+Vhc

    dim3 blk(256);

    // 0) mask compaction tables
    prep_kernel<<<dim3(Bn), blk, 0, stream>>>(k_mask, q_mask, kidx, kpos, qidx, qpos, cnts);

    // 1) fused weight prep: Wqt/Wkt transpose, Wvb convert, c
    wprep_kernel<<<dim3(1025), blk, 0, stream>>>(
        Wq, Wk, Wv, bq, bk, Wqt, Wkt, Wvb, cbuf);

    // 2) w1/w2 from bf16 transposed weights (coalesced, R11 form)
    wvec_kernel<<<dim3(256, 2), blk, 0, stream>>>(Wqt, Wkt, bk, bq, w1, w2);

    // 3) convert Q + fused u-dot; convert gathered K/V + fused vc-dot
    convq_kernel<<<dim3(BL), blk, 0, stream>>>(Q, w1, cbuf, Xq, uarr);
    convkv_kernel<<<dim3(Ln, 2, Bn), blk, 0, stream>>>(
        K, V, kidx, cnts, w2, Xkc, Vc, vc);

    // 4) Mb = Wq^T Wk (row-major M), bf16
    mgemm_kernel<<<dim3(8, 8), blk, 0, stream>>>(Wqt, Wkt, Mb);

    // 5) Gt[b] = Xkc[b] @ M^T (compacted rows); Vhc = Vc @ Wv^T + bv
    gt_kernel<<<dim3(Dn / 128, Ln / 128, Bn), blk, 0, stream>>>(Xkc, Mb, cnts, Gt);
    projv_kernel<<<dim3(Dn / 128, Ln / 128, Bn), blk, 0, stream>>>(
        Vc, Wvb, bv, cnts, Vhc);

    // 6) straight transpose of compacted V
    vtransc_kernel<<<dim3(Dn / 64, Ln / 64, Bn), blk, 0, stream>>>(Vhc, cnts, Vtc);

    // 7) compacted scores (Xq . Gt + u + vc) -> bf16 Ec (overwrites Vc/Xkc)
    scorec_kernel<<<dim3(2048), blk, 0, stream>>>(Xq, Gt, cnts, uarr, vc, Ec);

    // 8) fused stats + bf16 P emission + e expand + masked-q a zeroing
    stats_expand_kernel<<<dim3(BL), blk, 0, stream>>>(
        Ec, kpos, qpos, cnts, Pc, out_e, out_a);

    // 9) pure-GEMM PV
    pvc_kernel<<<dim3(1024), blk, 0, stream>>>(Pc, Vtc, qidx, cnts, out_a);
}

// Round 14
// 328.401 us; speedup vs baseline: 1.1188x; 1.0319x over previous
//
#include <hip/hip_runtime.h>
#include <cstddef>
#include <cstdint>

constexpr int Bn = 8;
constexpr int Ln = 2048;
constexpr int Dn = 1024;
constexpr float MASKED_VAL = -2147483648.0f;  // -2^31

typedef unsigned short u16;
typedef unsigned int   u32;
typedef __attribute__((ext_vector_type(8))) __bf16 bf16x8;
typedef __attribute__((ext_vector_type(4))) float  f32x4;

__device__ __forceinline__ u16 f2bf(float x) {
    u32 u = __float_as_uint(x);
    u += 0x7FFFu + ((u >> 16) & 1u);
    return (u16)(u >> 16);
}
__device__ __forceinline__ float bf2f(u16 h) {
    return __uint_as_float(((u32)h) << 16);
}
__device__ __forceinline__ u32 pack2(float a, float b) {
    return (u32)f2bf(a) | ((u32)f2bf(b) << 16);
}
__device__ __forceinline__ int rup(int x, int m) { return (x + m - 1) & ~(m - 1); }

__device__ __forceinline__ void gload16(const void* g, void* l) {
    typedef const __attribute__((address_space(1))) unsigned int* gp_t;
    typedef __attribute__((address_space(3))) unsigned int* lp_t;
    __builtin_amdgcn_global_load_lds((gp_t)g, (lp_t)l, 16, 0, 0);
}

#define MFMA16(a, b, c) __builtin_amdgcn_mfma_f32_16x16x32_bf16((a), (b), (c), 0, 0, 0)

// ---------------------------------------------------------------------------
// prep: per batch, compaction tables. kidx (padded w/ last valid), kpos
// (-1 if masked), qidx (padded w/ 0), qpos (-1 if masked), counts.
// ---------------------------------------------------------------------------
__global__ __launch_bounds__(256) void prep_kernel(
    const int* __restrict__ k_mask, const int* __restrict__ q_mask,
    int* __restrict__ kidx, int* __restrict__ kpos,
    int* __restrict__ qidx, int* __restrict__ qpos, int* __restrict__ cnts)
{
    __shared__ int sc[256];
    __shared__ int lastv;
    const int b = blockIdx.x, t = threadIdx.x;
    for (int pass = 0; pass < 2; ++pass) {
        const int* msk = (pass ? q_mask : k_mask) + b * Ln;
        int* idx = (pass ? qidx : kidx) + b * Ln;
        int* pos = (pass ? qpos : kpos) + b * Ln;
        int f[8], s = 0;
        #pragma unroll
        for (int j = 0; j < 8; ++j) { f[j] = (msk[t * 8 + j] != 0) ? 1 : 0; s += f[j]; }
        sc[t] = s;
        __syncthreads();
        #pragma unroll
        for (int o = 1; o < 256; o <<= 1) {
            int v = (t >= o) ? sc[t - o] : 0;
            __syncthreads();
            sc[t] += v;
            __syncthreads();
        }
        int incl = sc[t];
        int total = sc[255];
        int p = incl - s;
        #pragma unroll
        for (int j = 0; j < 8; ++j) {
            pos[t * 8 + j] = f[j] ? p : -1;
            if (f[j]) { idx[p] = t * 8 + j; ++p; }
        }
        __syncthreads();
        if (t == 0) {
            cnts[b * 2 + pass] = total;
            lastv = (total > 0) ? idx[total - 1] : 0;
        }
        __syncthreads();
        int padv = (pass == 0) ? lastv : 0;
        for (int e2 = total + t; e2 < Ln; e2 += 256) idx[e2] = padv;
        __syncthreads();
    }
}

// ---------------------------------------------------------------------------
// wprep: fused weight prep (streaming-clean parts only).
//   blocks [0,512):    wtrans Wq/Wk fp32 -> Wqt/Wkt bf16 [d][e]
//   blocks [512,1024): convert Wv -> Wvb bf16
//   block 1024:        cbuf[0] = bq.bk
// ---------------------------------------------------------------------------
__global__ __launch_bounds__(256) void wprep_kernel(
    const float* __restrict__ Wq, const float* __restrict__ Wk, const float* __restrict__ Wv,
    const float* __restrict__ bq, const float* __restrict__ bk,
    u16* __restrict__ Wqt, u16* __restrict__ Wkt, u16* __restrict__ Wvb,
    float* __restrict__ cbuf)
{
    __shared__ float tile[64][68];
    const int blk = blockIdx.x;
    const int t = threadIdx.x;

    if (blk < 512) {
        const float* src = (blk >= 256) ? Wk : Wq;
        u16* dst = (blk >= 256) ? Wkt : Wqt;
        const int rem = blk & 255;
        const int e0 = (rem >> 4) * 64, d0 = (rem & 15) * 64;
        const int r = t >> 2, cq = (t & 3) * 16;
        const float* s = src + (size_t)(e0 + r) * Dn + d0 + cq;
        #pragma unroll
        for (int i = 0; i < 4; ++i)
            *(float4*)&tile[r][cq + i * 4] = *(const float4*)(s + i * 4);
        __syncthreads();
        u32 o[8];
        #pragma unroll
        for (int i = 0; i < 8; ++i)
            o[i] = pack2(tile[cq + 2 * i][r], tile[cq + 2 * i + 1][r]);
        u16* d = dst + (size_t)(d0 + r) * Dn + e0 + cq;
        *(uint4*)(d)     = make_uint4(o[0], o[1], o[2], o[3]);
        *(uint4*)(d + 8) = make_uint4(o[4], o[5], o[6], o[7]);
    } else if (blk < 1024) {
        int i = ((blk - 512) * 256 + t) * 8;
        float f[8];
        *(float4*)&f[0] = *(const float4*)(Wv + i);
        *(float4*)&f[4] = *(const float4*)(Wv + i + 4);
        u32 H[4];
        #pragma unroll
        for (int j = 0; j < 4; ++j) H[j] = pack2(f[2*j], f[2*j+1]);
        *(uint4*)(Wvb + i) = make_uint4(H[0], H[1], H[2], H[3]);
    } else {
        if (t < 64) {
            float s = 0.f;
            #pragma unroll
            for (int i = 0; i < 16; ++i) s += bq[t + 64 * i] * bk[t + 64 * i];
            #pragma unroll
            for (int o = 32; o; o >>= 1) s += __shfl_xor(s, o, 64);
            if (t == 0) cbuf[0] = s;
        }
    }
}

// ---------------------------------------------------------------------------
// wmix: fused mgemm + wvec (both depend only on wprep).
//   blocks [0,64):   Mb[m][n] = sum_e Wqt[m,e]*Wkt[n,e]  (128^2 tile GEMM)
//   blocks [64,576): w1[d] = Wqt[d,:].bk ; w2[d] = Wkt[d,:].bq
// ---------------------------------------------------------------------------
__global__ __launch_bounds__(256) void wmix_kernel(
    const u16* __restrict__ Wqt, const u16* __restrict__ Wkt,
    const float* __restrict__ bk, const float* __restrict__ bq,
    float* __restrict__ w1, float* __restrict__ w2, u16* __restrict__ Mb)
{
    __shared__ __align__(16) unsigned char As[128 * 128];
    __shared__ __align__(16) unsigned char Bs[128 * 128];

    const int blk = blockIdx.x;

    if (blk >= 64) {
        // wvec part
        const int rel = blk - 64;
        const int y = rel >> 8;
        const int xb = rel & 255;
        const u16* src = y ? Wkt : Wqt;
        const float* vec = y ? bq : bk;
        float* out = y ? w2 : w1;
        const int d = xb * 4 + (threadIdx.x >> 6);
        const int l = threadIdx.x & 63;
        float s = 0.f;
        #pragma unroll
        for (int i = 0; i < 16; ++i) {
            int e = l + 64 * i;
            s += bf2f(src[(size_t)d * Dn + e]) * vec[e];
        }
        #pragma unroll
        for (int o = 32; o; o >>= 1) s += __shfl_xor(s, o, 64);
        if (l == 0) out[d] = s;
        return;
    }

    // mgemm part: m0 = (blk>>3)*128, n0 = (blk&7)*128
    const int m0 = (blk >> 3) * 128, n0 = (blk & 7) * 128;
    const int tid = threadIdx.x, lane = tid & 63, wid = tid >> 6;
    const int wm = (wid >> 1) * 64, wn = (wid & 1) * 64;

    const u16* gA[4]; const u16* gB[4]; int ldsOff[4];
    #pragma unroll
    for (int q = 0; q < 4; ++q) {
        int c = wid * 4 + q;
        int row = c * 8 + (lane >> 3);
        int sig = (lane & 7) ^ (row & 7);
        gA[q] = Wqt + (size_t)(m0 + row) * Dn + sig * 8;
        gB[q] = Wkt + (size_t)(n0 + row) * Dn + sig * 8;
        ldsOff[q] = c * 1024;
    }

    f32x4 acc[4][4];
    const f32x4 z4 = {0.f, 0.f, 0.f, 0.f};
    #pragma unroll
    for (int i = 0; i < 4; ++i)
        #pragma unroll
        for (int j = 0; j < 4; ++j) acc[i][j] = z4;

    for (int k0 = 0; k0 < Dn; k0 += 64) {
        #pragma unroll
        for (int q = 0; q < 4; ++q) {
            gload16(gA[q], As + ldsOff[q]);
            gload16(gB[q], Bs + ldsOff[q]);
            gA[q] += 64; gB[q] += 64;
        }
        __syncthreads();

        const int sh = lane >> 4;
        #pragma unroll
        for (int s = 0; s < 2; ++s) {
            bf16x8 af[4], bf[4];
            #pragma unroll
            for (int i = 0; i < 4; ++i) {
                int row = wm + i * 16 + (lane & 15);
                af[i] = *(const bf16x8*)(As + row * 128 + (((s * 4 + sh) ^ (row & 7)) << 4));
            }
            #pragma unroll
            for (int j = 0; j < 4; ++j) {
                int row = wn + j * 16 + (lane & 15);
                bf[j] = *(const bf16x8*)(Bs + row * 128 + (((s * 4 + sh) ^ (row & 7)) << 4));
            }
            #pragma unroll
            for (int i = 0; i < 4; ++i)
                #pragma unroll
                for (int j = 0; j < 4; ++j)
                    acc[i][j] = MFMA16(af[i], bf[j], acc[i][j]);
        }
        __syncthreads();
    }

    #pragma unroll
    for (int i = 0; i < 4; ++i) {
        #pragma unroll
        for (int r = 0; r < 4; ++r) {
            int m = m0 + wm + i * 16 + (lane >> 4) * 4 + r;
            u16* oh = Mb + (size_t)m * Dn + n0 + wn;
            #pragma unroll
            for (int j = 0; j < 4; ++j)
                oh[j * 16 + (lane & 15)] = f2bf(acc[i][j][r]);
        }
    }
}

// ---------------------------------------------------------------------------
// convmix: fused convq + convkv (both depend on wmix/prep).
//   blocks [0,16384):      Q row -> Xq bf16 + u[row] dot (w1) + c
//   blocks [16384,49152):  K/V gathered compacted rows -> Xkc/Vc (+vc dot w2)
// ---------------------------------------------------------------------------
__global__ __launch_bounds__(256) void convmix_kernel(
    const float* __restrict__ Q, const float* __restrict__ K, const float* __restrict__ V,
    const int* __restrict__ kidx, const int* __restrict__ cnts,
    const float* __restrict__ w1, const float* __restrict__ w2,
    const float* __restrict__ cbuf,
    u16* __restrict__ Xq, u16* __restrict__ Xkc, u16* __restrict__ Vc,
    float* __restrict__ u, float* __restrict__ vc)
{
    __shared__ float red[4];
    const int blk = blockIdx.x;
    const int t = threadIdx.x;

    if (blk < 16384) {
        // convq
        const int row = blk;
        float4 f = *(const float4*)(Q + (size_t)row * Dn + t * 4);
        u32 p0 = pack2(f.x, f.y), p1 = pack2(f.z, f.w);
        *(uint2*)(Xq + (size_t)row * Dn + t * 4) = make_uint2(p0, p1);

        float4 w = *(const float4*)(w1 + t * 4);
        float s = bf2f((u16)(p0 & 0xFFFFu)) * w.x + bf2f((u16)(p0 >> 16)) * w.y
                + bf2f((u16)(p1 & 0xFFFFu)) * w.z + bf2f((u16)(p1 >> 16)) * w.w;
        #pragma unroll
        for (int o = 32; o; o >>= 1) s += __shfl_xor(s, o, 64);
        if ((t & 63) == 0) red[t >> 6] = s;
        __syncthreads();
        if (t == 0) u[row] = red[0] + red[1] + red[2] + red[3] + cbuf[0];
    } else {
        // convkv
        const int rel = blk - 16384;
        const int j = rel & 2047;
        const int y = (rel >> 11) & 1;
        const int b = rel >> 12;
        if (j >= rup(cnts[b * 2], 128)) return;
        const int srow = kidx[b * Ln + j];
        float4 f = *(const float4*)((y ? V : K) + ((size_t)b * Ln + srow) * Dn + t * 4);
        u32 p0 = pack2(f.x, f.y), p1 = pack2(f.z, f.w);
        *(uint2*)((y ? Vc : Xkc) + ((size_t)b * Ln + j) * Dn + t * 4) = make_uint2(p0, p1);

        if (y == 0) {
            float4 w = *(const float4*)(w2 + t * 4);
            float s = bf2f((u16)(p0 & 0xFFFFu)) * w.x + bf2f((u16)(p0 >> 16)) * w.y
                    + bf2f((u16)(p1 & 0xFFFFu)) * w.z + bf2f((u16)(p1 >> 16)) * w.w;
            #pragma unroll
            for (int o = 32; o; o >>= 1) s += __shfl_xor(s, o, 64);
            if ((t & 63) == 0) red[t >> 6] = s;
            __syncthreads();
            if (t == 0) vc[b * Ln + j] = red[0] + red[1] + red[2] + red[3];
        }
    }
}

// ---------------------------------------------------------------------------
// gtpv: fused gt + projv (identical shapes, z in [0,16)).
//   z in [0,8):  Gt[b][j][:] = Xkc[b][j][:] @ Mb^T            (b = z)
//   z in [8,16): Vhc[b][j][:] = Vc[b][j][:] @ Wvb^T + bv      (b = z-8)
// Compacted rows only.
// ---------------------------------------------------------------------------
__global__ __launch_bounds__(256) void gtpv_kernel(
    const u16* __restrict__ Xkc, const u16* __restrict__ Vc,
    const u16* __restrict__ Mb, const u16* __restrict__ Wvb,
    const float* __restrict__ bv, const int* __restrict__ cnts,
    u16* __restrict__ Gt, u16* __restrict__ Vhc)
{
    __shared__ __align__(16) unsigned char As[128 * 128];
    __shared__ __align__(16) unsigned char Bs[128 * 128];

    const int z = blockIdx.z;
    const bool isV = (z >= 8);
    const int b = z & 7;
    const int kc_b = cnts[b * 2];
    const int m0 = blockIdx.y * 128;
    if (m0 >= rup(kc_b, 128)) return;
    const int n0 = blockIdx.x * 128;
    const int tid = threadIdx.x, lane = tid & 63, wid = tid >> 6;
    const int wm = (wid >> 1) * 64, wn = (wid & 1) * 64;

    const u16* Ab = (isV ? Vc : Xkc) + (size_t)b * Ln * Dn;
    const u16* Bb = isV ? Wvb : Mb;
    u16* Cb = (isV ? Vhc : Gt) + (size_t)b * Ln * Dn;

    const u16* gA[4]; const u16* gB[4]; int ldsOff[4];
    #pragma unroll
    for (int q = 0; q < 4; ++q) {
        int c = wid * 4 + q;
        int row = c * 8 + (lane >> 3);
        int sig = (lane & 7) ^ (row & 7);
        gA[q] = Ab + (size_t)(m0 + row) * Dn + sig * 8;
        gB[q] = Bb + (size_t)(n0 + row) * Dn + sig * 8;
        ldsOff[q] = c * 1024;
    }

    f32x4 acc[4][4];
    const f32x4 z4 = {0.f, 0.f, 0.f, 0.f};
    #pragma unroll
    for (int i = 0; i < 4; ++i)
        #pragma unroll
        for (int j = 0; j < 4; ++j) acc[i][j] = z4;

    for (int k0 = 0; k0 < Dn; k0 += 64) {
        #pragma unroll
        for (int q = 0; q < 4; ++q) {
            gload16(gA[q], As + ldsOff[q]);
            gload16(gB[q], Bs + ldsOff[q]);
            gA[q] += 64; gB[q] += 64;
        }
        __syncthreads();

        const int sh = lane >> 4;
        #pragma unroll
        for (int s = 0; s < 2; ++s) {
            bf16x8 af[4], bf[4];
            #pragma unroll
            for (int i = 0; i < 4; ++i) {
                int row = wm + i * 16 + (lane & 15);
                af[i] = *(const bf16x8*)(As + row * 128 + (((s * 4 + sh) ^ (row & 7)) << 4));
            }
            #pragma unroll
            for (int j = 0; j < 4; ++j) {
                int row = wn + j * 16 + (lane & 15);
                bf[j] = *(const bf16x8*)(Bs + row * 128 + (((s * 4 + sh) ^ (row & 7)) << 4));
            }
            #pragma unroll
            for (int i = 0; i < 4; ++i)
                #pragma unroll
                for (int j = 0; j < 4; ++j)
                    acc[i][j] = MFMA16(af[i], bf[j], acc[i][j]);
        }
        __syncthreads();
    }

    float bv4[4];
    #pragma unroll
    for (int j = 0; j < 4; ++j)
        bv4[j] = isV ? bv[n0 + wn + j * 16 + (lane & 15)] : 0.0f;
    #pragma unroll
    for (int i = 0; i < 4; ++i) {
        #pragma unroll
        for (int r = 0; r < 4; ++r) {
            int m = m0 + wm + i * 16 + (lane >> 4) * 4 + r;
            u16* oh = Cb + (size_t)m * Dn + n0 + wn;
            #pragma unroll
            for (int j = 0; j < 4; ++j) {
                float val = acc[i][j][r];
                if (isV) val += bv4[j];
                oh[j * 16 + (lane & 15)] = f2bf(val);
            }
        }
    }
}

// ---------------------------------------------------------------------------
// vtransc: Vtc[b][d][j] = Vhc[b][j][d]  (straight transpose, compacted rows)
// ---------------------------------------------------------------------------
__global__ __launch_bounds__(256) void vtransc_kernel(
    const u16* __restrict__ Vhc, const int* __restrict__ cnts,
    u16* __restrict__ Vtc)
{
    __shared__ u16 tile[64][72];
    const int b = blockIdx.z;
    const int l0 = blockIdx.y * 64, d0 = blockIdx.x * 64;
    if (l0 >= rup(cnts[b * 2], 64)) return;
    const int t = threadIdx.x;
    const int r = t >> 2, cq = (t & 3) * 16;

    const u16* src = Vhc + (size_t)(b * Ln + l0 + r) * Dn + d0 + cq;
    *(uint4*)&tile[r][cq]     = *(const uint4*)(src);
    *(uint4*)&tile[r][cq + 8] = *(const uint4*)(src + 8);
    __syncthreads();

    u16 tmp[16];
    #pragma unroll
    for (int i = 0; i < 16; ++i) tmp[i] = tile[cq + i][r];
    u16* dst = Vtc + (size_t)b * Dn * Ln + (size_t)(d0 + r) * Ln + l0 + cq;
    *(uint4*)(dst)     = *(uint4*)&tmp[0];
    *(uint4*)(dst + 8) = *(uint4*)&tmp[8];
}

// ---------------------------------------------------------------------------
// scorec: Ec[b,q,j] = bf16( Xq[b,q,:].Gt[b,j,:] + u[b,q] + vc[b,j] )
// for compacted j < kc; pad cols get bf16(MASKED). All-linear staging.
// XCD-chunked 1D grid (2048).
// ---------------------------------------------------------------------------
__global__ __launch_bounds__(256) void scorec_kernel(
    const u16* __restrict__ Xq, const u16* __restrict__ Gt,
    const int* __restrict__ cnts,
    const float* __restrict__ u, const float* __restrict__ vc,
    u16* __restrict__ Ec)
{
    __shared__ __align__(16) unsigned char As[128 * 128];
    __shared__ __align__(16) unsigned char Bs[128 * 128];

    // swizzle: nwg = 2048 = 8 * 256
    const int d = blockIdx.x;
    const int f = (d & 7) * 256 + (d >> 3);
    const int b = f >> 8;
    const int rem = f & 255;
    const int m0 = (rem >> 4) * 128;  // 16 q-tiles
    const int n0 = (rem & 15) * 128;  // 16 k-tiles

    const int kc_b = cnts[b * 2];
    if (n0 >= kc_b) return;
    const int tid = threadIdx.x, lane = tid & 63, wid = tid >> 6;
    const int wm = (wid >> 1) * 64, wn = (wid & 1) * 64;

    const size_t boff = (size_t)b * Ln * Dn;
    const u16* Xq_b = Xq + boff;
    const u16* Gt_b = Gt + boff;

    const u16* gA[4]; const u16* gB[4]; int ldsOff[4];
    #pragma unroll
    for (int q = 0; q < 4; ++q) {
        int c = wid * 4 + q;
        int row = c * 8 + (lane >> 3);
        int sig = (lane & 7) ^ (row & 7);
        gA[q] = Xq_b + (size_t)(m0 + row) * Dn + sig * 8;
        gB[q] = Gt_b + (size_t)(n0 + row) * Dn + sig * 8;
        ldsOff[q] = c * 1024;
    }

    f32x4 acc[4][4];
    const f32x4 z4 = {0.f, 0.f, 0.f, 0.f};
    #pragma unroll
    for (int i = 0; i < 4; ++i)
        #pragma unroll
        for (int j = 0; j < 4; ++j) acc[i][j] = z4;

    for (int k0 = 0; k0 < Dn; k0 += 64) {
        #pragma unroll
        for (int q = 0; q < 4; ++q) {
            gload16(gA[q], As + ldsOff[q]);
            gload16(gB[q], Bs + ldsOff[q]);
            gA[q] += 64; gB[q] += 64;
        }
        __syncthreads();

        const int sh = lane >> 4;
        #pragma unroll
        for (int s = 0; s < 2; ++s) {
            bf16x8 af[4], bf[4];
            #pragma unroll
            for (int i = 0; i < 4; ++i) {
                int row = wm + i * 16 + (lane & 15);
                af[i] = *(const bf16x8*)(As + row * 128 + (((s * 4 + sh) ^ (row & 7)) << 4));
            }
            #pragma unroll
            for (int j = 0; j < 4; ++j) {
                int row = wn + j * 16 + (lane & 15);
                bf[j] = *(const bf16x8*)(Bs + row * 128 + (((s * 4 + sh) ^ (row & 7)) << 4));
            }
            #pragma unroll
            for (int i = 0; i < 4; ++i)
                #pragma unroll
                for (int j = 0; j < 4; ++j)
                    acc[i][j] = MFMA16(af[i], bf[j], acc[i][j]);
        }
        __syncthreads();
    }

    float vcl[4];
    #pragma unroll
    for (int j = 0; j < 4; ++j) vcl[j] = vc[b * Ln + n0 + wn + j * 16 + (lane & 15)];
    #pragma unroll
    for (int i = 0; i < 4; ++i) {
        #pragma unroll
        for (int r = 0; r < 4; ++r) {
            int m = m0 + wm + i * 16 + (lane >> 4) * 4 + r;
            float um = u[b * Ln + m];
            u16* orow = Ec + ((size_t)(b * Ln + m)) * Ln + n0 + wn;
            #pragma unroll
            for (int j = 0; j < 4; ++j) {
                int jj = n0 + wn + j * 16 + (lane & 15);
                orow[j * 16 + (lane & 15)] =
                    f2bf((jj < kc_b) ? (acc[i][j][r] + um + vcl[j]) : MASKED_VAL);
            }
        }
    }
}

// ---------------------------------------------------------------------------
// stats_expand: one block per (b,q) row.
// If q-unmasked: block-reduce max/sum, write bf16 P row (q-compacted layout).
// Else: zero the out_a row.
// Always: expand bf16 Ec row -> full masked f32 e row (kpos gather).
// ---------------------------------------------------------------------------
__global__ __launch_bounds__(256) void stats_expand_kernel(
    const u16* __restrict__ Ec, const int* __restrict__ kpos,
    const int* __restrict__ qpos, const int* __restrict__ cnts,
    u16* __restrict__ Pc, float* __restrict__ e, float* __restrict__ out_a)
{
    __shared__ float redm[4];
    __shared__ float reds[4];
    const int row = blockIdx.x;
    const int b = row >> 11;
    const int t = threadIdx.x;
    const u16* er = Ec + (size_t)row * Ln;
    const int qp = qpos[row];

    if (qp >= 0) {
        const int bound = rup(cnts[b * 2], 64);
        const int lane = t & 63, wave = t >> 6;
        float v[8];
        int base = t * 8;
        if (base < bound) {
            uint4 x = *(const uint4*)(er + base);
            const u16* xs = (const u16*)&x;
            #pragma unroll
            for (int j = 0; j < 8; ++j) v[j] = bf2f(xs[j]);
        } else {
            #pragma unroll
            for (int j = 0; j < 8; ++j) v[j] = MASKED_VAL;
        }

        float mx = v[0];
        #pragma unroll
        for (int j = 1; j < 8; ++j) mx = fmaxf(mx, v[j]);
        #pragma unroll
        for (int o = 32; o > 0; o >>= 1) mx = fmaxf(mx, __shfl_xor(mx, o, 64));
        if (lane == 0) redm[wave] = mx;
        __syncthreads();
        mx = fmaxf(fmaxf(redm[0], redm[1]), fmaxf(redm[2], redm[3]));

        float s = 0.f;
        #pragma unroll
        for (int j = 0; j < 8; ++j) s += __expf(v[j] - mx);
        #pragma unroll
        for (int o = 32; o > 0; o >>= 1) s += __shfl_xor(s, o, 64);
        if (lane == 0) reds[wave] = s;
        __syncthreads();
        s = reds[0] + reds[1] + reds[2] + reds[3];
        float sinv = 1.0f / s;

        u32 P[4];
        #pragma unroll
        for (int j = 0; j < 4; ++j)
            P[j] = pack2(__expf(v[2*j] - mx) * sinv, __expf(v[2*j+1] - mx) * sinv);
        u16* pr = Pc + ((size_t)b * Ln + qp) * Ln + t * 8;
        *(uint4*)pr = make_uint4(P[0], P[1], P[2], P[3]);
    } else {
        *(float4*)(out_a + (size_t)row * Dn + t * 4) = make_float4(0.f, 0.f, 0.f, 0.f);
    }

    // expansion (reads Ec, writes e; independent of P path)
    const int* kp = kpos + b * Ln;
    const int k = t * 8;
    int p[8];
    *(int4*)&p[0] = *(const int4*)(kp + k);
    *(int4*)&p[4] = *(const int4*)(kp + k + 4);
    float o[8];
    #pragma unroll
    for (int j = 0; j < 8; ++j)
        o[j] = (p[j] >= 0) ? bf2f(er[p[j]]) : MASKED_VAL;

    float* eo = e + (size_t)row * Ln + k;
    *(float4*)(eo)     = make_float4(o[0], o[1], o[2], o[3]);
    *(float4*)(eo + 4) = make_float4(o[4], o[5], o[6], o[7]);
}

// ---------------------------------------------------------------------------
// pvc: a[qidx[i], :] = Pc[b,i,:] @ Vtc^T over compacted k. Pure GEMM.
// XCD-chunked grid (1024).
// ---------------------------------------------------------------------------
__global__ __launch_bounds__(256) void pvc_kernel(
    const u16* __restrict__ Pc, const u16* __restrict__ Vtc,
    const int* __restrict__ qidx, const int* __restrict__ cnts,
    float* __restrict__ out_a)
{
    __shared__ __align__(16) unsigned char As[128 * 128];
    __shared__ __align__(16) unsigned char Bs[128 * 128];

    // swizzle: nwg = 1024 = 8 * 128
    const int d = blockIdx.x;
    const int f = (d & 7) * 128 + (d >> 3);
    const int b = f >> 7;
    const int rem = f & 127;
    const int m0 = (rem >> 3) * 128;  // 16 compacted q tiles
    const int n0 = (rem & 7) * 128;   // 8 d tiles

    const int kc_b = cnts[b * 2], qc_b = cnts[b * 2 + 1];
    if (m0 >= rup(qc_b, 128)) return;
    const int kbound = rup(kc_b, 64);
    const int tid = threadIdx.x, lane = tid & 63, wid = tid >> 6;
    const int wm = (wid >> 1) * 64, wn = (wid & 1) * 64;

    const u16* Pc_b  = Pc  + (size_t)b * Ln * Ln;
    const u16* Vtc_b = Vtc + (size_t)b * Dn * Ln;
    const int* qidx_b = qidx + b * Ln;

    const u16* gA[4]; const u16* gB[4]; int ldsOff[4];
    #pragma unroll
    for (int q = 0; q < 4; ++q) {
        int c = wid * 4 + q;
        int row = c * 8 + (lane >> 3);
        int sig = (lane & 7) ^ (row & 7);
        gA[q] = Pc_b  + (size_t)(m0 + row) * Ln + sig * 8;
        gB[q] = Vtc_b + (size_t)(n0 + row) * Ln + sig * 8;
        ldsOff[q] = c * 1024;
    }

    f32x4 acc[4][4];
    const f32x4 z4 = {0.f, 0.f, 0.f, 0.f};
    #pragma unroll
    for (int i = 0; i < 4; ++i)
        #pragma unroll
        for (int j = 0; j < 4; ++j) acc[i][j] = z4;

    for (int k0 = 0; k0 < kbound; k0 += 64) {
        #pragma unroll
        for (int q = 0; q < 4; ++q) {
            gload16(gA[q], As + ldsOff[q]);
            gload16(gB[q], Bs + ldsOff[q]);
            gA[q] += 64; gB[q] += 64;
        }
        __syncthreads();

        const int sh = lane >> 4;
        #pragma unroll
        for (int s = 0; s < 2; ++s) {
            bf16x8 af[4], bv[4];
            #pragma unroll
            for (int i = 0; i < 4; ++i) {
                int row = wm + i * 16 + (lane & 15);
                af[i] = *(const bf16x8*)(As + row * 128 + (((s * 4 + sh) ^ (row & 7)) << 4));
            }
            #pragma unroll
            for (int j = 0; j < 4; ++j) {
                int row = wn + j * 16 + (lane & 15);
                bv[j] = *(const bf16x8*)(Bs + row * 128 + (((s * 4 + sh) ^ (row & 7)) << 4));
            }
            #pragma unroll
            for (int i = 0; i < 4; ++i)
                #pragma unroll
                for (int j = 0; j < 4; ++j)
                    acc[i][j] = MFMA16(af[i], bv[j], acc[i][j]);
        }
        __syncthreads();
    }

    #pragma unroll
    for (int i = 0; i < 4; ++i) {
        #pragma unroll
        for (int r = 0; r < 4; ++r) {
            int gi = m0 + wm + i * 16 + (lane >> 4) * 4 + r;
            if (gi < qc_b) {
                int gm = qidx_b[gi];
                float* orow = out_a + (size_t)(b * Ln + gm) * Dn + n0 + wn;
                #pragma unroll
                for (int j = 0; j < 4; ++j)
                    orow[j * 16 + (lane & 15)] = acc[i][j][r];
            }
        }
    }
}

// ---------------------------------------------------------------------------
extern "C" void kernel_launch(void* const* d_in, const int* in_sizes, int n_in,
                              void* d_out, int out_size, void* d_ws, size_t ws_size,
                              hipStream_t stream)
{
    const float* Q  = (const float*)d_in[0];
    const float* K  = (const float*)d_in[1];
    const float* V  = (const float*)d_in[2];
    const float* Wq = (const float*)d_in[3];
    const float* bq = (const float*)d_in[4];
    const float* Wk = (const float*)d_in[5];
    const float* bk = (const float*)d_in[6];
    const float* Wv = (const float*)d_in[7];
    const float* bv = (const float*)d_in[8];
    const int* q_mask = (const int*)d_in[9];
    const int* k_mask = (const int*)d_in[10];

    float* out_a = (float*)d_out;                       // [B, L, D]
    float* out_e = out_a + (size_t)Bn * Ln * Dn;        // [B, L, L]

    const size_t NE = (size_t)Bn * Ln * Dn;             // 16,777,216
    const size_t NW = (size_t)Dn * Dn;                  // 1,048,576
    const int BL = Bn * Ln;                             // 16,384

    // ws layout (aliasing plan):
    //   [Vc, Xkc]  -> aliased by Ec (bf16 e', 2*NE) after both are dead
    //   [Gt, Vhc]  -> aliased by Pc (bf16 P,  2*NE) after both are dead
    //   Xq, Vtc, Wvb, Wqt, Wkt, Mb, small tables
    u16* Vc  = (u16*)d_ws;
    u16* Xkc = Vc + NE;
    u16* Gt  = Xkc + NE;
    u16* Vhc = Gt + NE;
    u16* Xq  = Vhc + NE;
    u16* Vtc = Xq + NE;
    u16* Wvb = Vtc + NE;
    u16* Wqt = Wvb + NW;
    u16* Wkt = Wqt + NW;
    u16* Mb  = Wkt + NW;
    float* w1    = (float*)(Mb + NW);
    float* w2    = w1 + Dn;
    float* cbuf  = w2 + Dn;
    float* uarr  = cbuf + 4;
    float* vc    = uarr + BL;
    int* kidx = (int*)(vc + BL);
    int* kpos = kidx + BL;
    int* qidx = kpos + BL;
    int* qpos = qidx + BL;
    int* cnts = qpos + BL;

    u16* Ec = Vc;   // [B][L][L] bf16, aliases Vc+Xkc (dead after gtpv)
    u16* Pc = Gt;   // [B][L][L] bf16 (q-compacted rows), aliases Gt+Vhc

    dim3 blk(256);

    // 0) mask compaction tables
    prep_kernel<<<dim3(Bn), blk, 0, stream>>>(k_mask, q_mask, kidx, kpos, qidx, qpos, cnts);

    // 1) fused weight prep: Wqt/Wkt transpose, Wvb convert, c
    wprep_kernel<<<dim3(1025), blk, 0, stream>>>(
        Wq, Wk, Wv, bq, bk, Wqt, Wkt, Wvb, cbuf);

    // 2) fused mgemm (Mb = Wq^T Wk) + wvec (w1/w2)
    wmix_kernel<<<dim3(576), blk, 0, stream>>>(Wqt, Wkt, bk, bq, w1, w2, Mb);

    // 3) fused convert Q (+u) and gathered K/V (+vc)
    convmix_kernel<<<dim3(49152), blk, 0, stream>>>(
        Q, K, V, kidx, cnts, w1, w2, cbuf, Xq, Xkc, Vc, uarr, vc);

    // 4) fused Gt = Xkc@M^T and Vhc = Vc@Wv^T + bv (compacted rows)
    gtpv_kernel<<<dim3(Dn / 128, Ln / 128, 16), blk, 0, stream>>>(
        Xkc, Vc, Mb, Wvb, bv, cnts, Gt, Vhc);

    // 5) straight transpose of compacted V
    vtransc_kernel<<<dim3(Dn / 64, Ln / 64, Bn), blk, 0, stream>>>(Vhc, cnts, Vtc);

    // 6) compacted scores (Xq . Gt + u + vc) -> bf16 Ec (overwrites Vc/Xkc)
    scorec_kernel<<<dim3(2048), blk, 0, stream>>>(Xq, Gt, cnts, uarr, vc, Ec);

    // 7) fused stats + bf16 P emission + e expand + masked-q a zeroing
    stats_expand_kernel<<<dim3(BL), blk, 0, stream>>>(
        Ec, kpos, qpos, cnts, Pc, out_e, out_a);

    // 8) pure-GEMM PV
    pvc_kernel<<<dim3(1024), blk, 0, stream>>>(Pc, Vtc, qidx, cnts, out_a);
}

// Round 15
// 314.640 us; speedup vs baseline: 1.1677x; 1.0437x over previous
//
#include <hip/hip_runtime.h>
#include <cstddef>
#include <cstdint>

constexpr int Bn = 8;
constexpr int Ln = 2048;
constexpr int Dn = 1024;
constexpr float MASKED_VAL = -2147483648.0f;  // -2^31

typedef unsigned short u16;
typedef unsigned int   u32;
typedef __attribute__((ext_vector_type(8))) __bf16 bf16x8;
typedef __attribute__((ext_vector_type(4))) float  f32x4;

__device__ __forceinline__ u16 f2bf(float x) {
    u32 u = __float_as_uint(x);
    u += 0x7FFFu + ((u >> 16) & 1u);
    return (u16)(u >> 16);
}
__device__ __forceinline__ float bf2f(u16 h) {
    return __uint_as_float(((u32)h) << 16);
}
__device__ __forceinline__ u32 pack2(float a, float b) {
    return (u32)f2bf(a) | ((u32)f2bf(b) << 16);
}
__device__ __forceinline__ int rup(int x, int m) { return (x + m - 1) & ~(m - 1); }

__device__ __forceinline__ void gload16(const void* g, void* l) {
    typedef const __attribute__((address_space(1))) unsigned int* gp_t;
    typedef __attribute__((address_space(3))) unsigned int* lp_t;
    __builtin_amdgcn_global_load_lds((gp_t)g, (lp_t)l, 16, 0, 0);
}

#define MFMA16(a, b, c) __builtin_amdgcn_mfma_f32_16x16x32_bf16((a), (b), (c), 0, 0, 0)

// ---------------------------------------------------------------------------
// prepw: fused prep (blocks [0,8)) + weight prep (blocks [8,1033)).
//   prep: per batch compaction tables.
//   wprep: blocks [8,520) wtrans Wq/Wk; [520,1032) convert Wv; 1032: c.
// ---------------------------------------------------------------------------
__global__ __launch_bounds__(256) void prepw_kernel(
    const int* __restrict__ k_mask, const int* __restrict__ q_mask,
    const float* __restrict__ Wq, const float* __restrict__ Wk, const float* __restrict__ Wv,
    const float* __restrict__ bq, const float* __restrict__ bk,
    int* __restrict__ kidx, int* __restrict__ kpos,
    int* __restrict__ qidx, int* __restrict__ qpos, int* __restrict__ cnts,
    u16* __restrict__ Wqt, u16* __restrict__ Wkt, u16* __restrict__ Wvb,
    float* __restrict__ cbuf)
{
    __shared__ __align__(16) unsigned char lds[64 * 68 * 4];
    const int blk0 = blockIdx.x;
    const int t = threadIdx.x;

    if (blk0 < 8) {
        // ---- prep (per batch) ----
        int* sc = (int*)lds;
        int* lastvp = sc + 256;
        const int b = blk0;
        for (int pass = 0; pass < 2; ++pass) {
            const int* msk = (pass ? q_mask : k_mask) + b * Ln;
            int* idx = (pass ? qidx : kidx) + b * Ln;
            int* pos = (pass ? qpos : kpos) + b * Ln;
            int f[8], s = 0;
            #pragma unroll
            for (int j = 0; j < 8; ++j) { f[j] = (msk[t * 8 + j] != 0) ? 1 : 0; s += f[j]; }
            sc[t] = s;
            __syncthreads();
            #pragma unroll
            for (int o = 1; o < 256; o <<= 1) {
                int v = (t >= o) ? sc[t - o] : 0;
                __syncthreads();
                sc[t] += v;
                __syncthreads();
            }
            int incl = sc[t];
            int total = sc[255];
            int p = incl - s;
            #pragma unroll
            for (int j = 0; j < 8; ++j) {
                pos[t * 8 + j] = f[j] ? p : -1;
                if (f[j]) { idx[p] = t * 8 + j; ++p; }
            }
            __syncthreads();
            if (t == 0) {
                cnts[b * 2 + pass] = total;
                lastvp[0] = (total > 0) ? idx[total - 1] : 0;
            }
            __syncthreads();
            int padv = (pass == 0) ? lastvp[0] : 0;
            for (int e2 = total + t; e2 < Ln; e2 += 256) idx[e2] = padv;
            __syncthreads();
        }
        return;
    }

    const int blk = blk0 - 8;
    if (blk < 512) {
        float (*tile)[68] = (float(*)[68])lds;
        const float* src = (blk >= 256) ? Wk : Wq;
        u16* dst = (blk >= 256) ? Wkt : Wqt;
        const int rem = blk & 255;
        const int e0 = (rem >> 4) * 64, d0 = (rem & 15) * 64;
        const int r = t >> 2, cq = (t & 3) * 16;
        const float* s = src + (size_t)(e0 + r) * Dn + d0 + cq;
        #pragma unroll
        for (int i = 0; i < 4; ++i)
            *(float4*)&tile[r][cq + i * 4] = *(const float4*)(s + i * 4);
        __syncthreads();
        u32 o[8];
        #pragma unroll
        for (int i = 0; i < 8; ++i)
            o[i] = pack2(tile[cq + 2 * i][r], tile[cq + 2 * i + 1][r]);
        u16* d = dst + (size_t)(d0 + r) * Dn + e0 + cq;
        *(uint4*)(d)     = make_uint4(o[0], o[1], o[2], o[3]);
        *(uint4*)(d + 8) = make_uint4(o[4], o[5], o[6], o[7]);
    } else if (blk < 1024) {
        int i = ((blk - 512) * 256 + t) * 8;
        float f[8];
        *(float4*)&f[0] = *(const float4*)(Wv + i);
        *(float4*)&f[4] = *(const float4*)(Wv + i + 4);
        u32 H[4];
        #pragma unroll
        for (int j = 0; j < 4; ++j) H[j] = pack2(f[2*j], f[2*j+1]);
        *(uint4*)(Wvb + i) = make_uint4(H[0], H[1], H[2], H[3]);
    } else {
        if (t < 64) {
            float s = 0.f;
            #pragma unroll
            for (int i = 0; i < 16; ++i) s += bq[t + 64 * i] * bk[t + 64 * i];
            #pragma unroll
            for (int o = 32; o; o >>= 1) s += __shfl_xor(s, o, 64);
            if (t == 0) cbuf[0] = s;
        }
    }
}

// ---------------------------------------------------------------------------
// wmix: fused mgemm + wvec (both depend only on prepw).
//   blocks [0,64):   Mb[m][n] = sum_e Wqt[m,e]*Wkt[n,e]  (128^2 tile GEMM)
//   blocks [64,576): w1[d] = Wqt[d,:].bk ; w2[d] = Wkt[d,:].bq
// ---------------------------------------------------------------------------
__global__ __launch_bounds__(256) void wmix_kernel(
    const u16* __restrict__ Wqt, const u16* __restrict__ Wkt,
    const float* __restrict__ bk, const float* __restrict__ bq,
    float* __restrict__ w1, float* __restrict__ w2, u16* __restrict__ Mb)
{
    __shared__ __align__(16) unsigned char As[128 * 128];
    __shared__ __align__(16) unsigned char Bs[128 * 128];

    const int blk = blockIdx.x;

    if (blk >= 64) {
        const int rel = blk - 64;
        const int y = rel >> 8;
        const int xb = rel & 255;
        const u16* src = y ? Wkt : Wqt;
        const float* vec = y ? bq : bk;
        float* out = y ? w2 : w1;
        const int d = xb * 4 + (threadIdx.x >> 6);
        const int l = threadIdx.x & 63;
        float s = 0.f;
        #pragma unroll
        for (int i = 0; i < 16; ++i) {
            int e = l + 64 * i;
            s += bf2f(src[(size_t)d * Dn + e]) * vec[e];
        }
        #pragma unroll
        for (int o = 32; o; o >>= 1) s += __shfl_xor(s, o, 64);
        if (l == 0) out[d] = s;
        return;
    }

    const int m0 = (blk >> 3) * 128, n0 = (blk & 7) * 128;
    const int tid = threadIdx.x, lane = tid & 63, wid = tid >> 6;
    const int wm = (wid >> 1) * 64, wn = (wid & 1) * 64;

    const u16* gA[4]; const u16* gB[4]; int ldsOff[4];
    #pragma unroll
    for (int q = 0; q < 4; ++q) {
        int c = wid * 4 + q;
        int row = c * 8 + (lane >> 3);
        int sig = (lane & 7) ^ (row & 7);
        gA[q] = Wqt + (size_t)(m0 + row) * Dn + sig * 8;
        gB[q] = Wkt + (size_t)(n0 + row) * Dn + sig * 8;
        ldsOff[q] = c * 1024;
    }

    f32x4 acc[4][4];
    const f32x4 z4 = {0.f, 0.f, 0.f, 0.f};
    #pragma unroll
    for (int i = 0; i < 4; ++i)
        #pragma unroll
        for (int j = 0; j < 4; ++j) acc[i][j] = z4;

    for (int k0 = 0; k0 < Dn; k0 += 64) {
        #pragma unroll
        for (int q = 0; q < 4; ++q) {
            gload16(gA[q], As + ldsOff[q]);
            gload16(gB[q], Bs + ldsOff[q]);
            gA[q] += 64; gB[q] += 64;
        }
        __syncthreads();

        const int sh = lane >> 4;
        #pragma unroll
        for (int s = 0; s < 2; ++s) {
            bf16x8 af[4], bf[4];
            #pragma unroll
            for (int i = 0; i < 4; ++i) {
                int row = wm + i * 16 + (lane & 15);
                af[i] = *(const bf16x8*)(As + row * 128 + (((s * 4 + sh) ^ (row & 7)) << 4));
            }
            #pragma unroll
            for (int j = 0; j < 4; ++j) {
                int row = wn + j * 16 + (lane & 15);
                bf[j] = *(const bf16x8*)(Bs + row * 128 + (((s * 4 + sh) ^ (row & 7)) << 4));
            }
            #pragma unroll
            for (int i = 0; i < 4; ++i)
                #pragma unroll
                for (int j = 0; j < 4; ++j)
                    acc[i][j] = MFMA16(af[i], bf[j], acc[i][j]);
        }
        __syncthreads();
    }

    #pragma unroll
    for (int i = 0; i < 4; ++i) {
        #pragma unroll
        for (int r = 0; r < 4; ++r) {
            int m = m0 + wm + i * 16 + (lane >> 4) * 4 + r;
            u16* oh = Mb + (size_t)m * Dn + n0 + wn;
            #pragma unroll
            for (int j = 0; j < 4; ++j)
                oh[j * 16 + (lane & 15)] = f2bf(acc[i][j][r]);
        }
    }
}

// ---------------------------------------------------------------------------
// convmix: fused convq + convkv.
//   blocks [0,16384):      Q row -> Xq bf16 + u[row] dot (w1) + c
//   blocks [16384,49152):  K/V gathered compacted rows -> Xkc/Vc (+vc dot w2)
// ---------------------------------------------------------------------------
__global__ __launch_bounds__(256) void convmix_kernel(
    const float* __restrict__ Q, const float* __restrict__ K, const float* __restrict__ V,
    const int* __restrict__ kidx, const int* __restrict__ cnts,
    const float* __restrict__ w1, const float* __restrict__ w2,
    const float* __restrict__ cbuf,
    u16* __restrict__ Xq, u16* __restrict__ Xkc, u16* __restrict__ Vc,
    float* __restrict__ u, float* __restrict__ vc)
{
    __shared__ float red[4];
    const int blk = blockIdx.x;
    const int t = threadIdx.x;

    if (blk < 16384) {
        const int row = blk;
        float4 f = *(const float4*)(Q + (size_t)row * Dn + t * 4);
        u32 p0 = pack2(f.x, f.y), p1 = pack2(f.z, f.w);
        *(uint2*)(Xq + (size_t)row * Dn + t * 4) = make_uint2(p0, p1);

        float4 w = *(const float4*)(w1 + t * 4);
        float s = bf2f((u16)(p0 & 0xFFFFu)) * w.x + bf2f((u16)(p0 >> 16)) * w.y
                + bf2f((u16)(p1 & 0xFFFFu)) * w.z + bf2f((u16)(p1 >> 16)) * w.w;
        #pragma unroll
        for (int o = 32; o; o >>= 1) s += __shfl_xor(s, o, 64);
        if ((t & 63) == 0) red[t >> 6] = s;
        __syncthreads();
        if (t == 0) u[row] = red[0] + red[1] + red[2] + red[3] + cbuf[0];
    } else {
        const int rel = blk - 16384;
        const int j = rel & 2047;
        const int y = (rel >> 11) & 1;
        const int b = rel >> 12;
        if (j >= rup(cnts[b * 2], 128)) return;
        const int srow = kidx[b * Ln + j];
        float4 f = *(const float4*)((y ? V : K) + ((size_t)b * Ln + srow) * Dn + t * 4);
        u32 p0 = pack2(f.x, f.y), p1 = pack2(f.z, f.w);
        *(uint2*)((y ? Vc : Xkc) + ((size_t)b * Ln + j) * Dn + t * 4) = make_uint2(p0, p1);

        if (y == 0) {
            float4 w = *(const float4*)(w2 + t * 4);
            float s = bf2f((u16)(p0 & 0xFFFFu)) * w.x + bf2f((u16)(p0 >> 16)) * w.y
                    + bf2f((u16)(p1 & 0xFFFFu)) * w.z + bf2f((u16)(p1 >> 16)) * w.w;
            #pragma unroll
            for (int o = 32; o; o >>= 1) s += __shfl_xor(s, o, 64);
            if ((t & 63) == 0) red[t >> 6] = s;
            __syncthreads();
            if (t == 0) vc[b * Ln + j] = red[0] + red[1] + red[2] + red[3];
        }
    }
}

// ---------------------------------------------------------------------------
// gtpv: fused gt + projv (identical shapes, z in [0,16)).
//   z in [0,8):  Gt[b][j][:] = Xkc[b][j][:] @ Mb^T            (b = z)
//   z in [8,16): Vhc[b][j][:] = Vc[b][j][:] @ Wvb^T + bv      (b = z-8)
// ---------------------------------------------------------------------------
__global__ __launch_bounds__(256) void gtpv_kernel(
    const u16* __restrict__ Xkc, const u16* __restrict__ Vc,
    const u16* __restrict__ Mb, const u16* __restrict__ Wvb,
    const float* __restrict__ bv, const int* __restrict__ cnts,
    u16* __restrict__ Gt, u16* __restrict__ Vhc)
{
    __shared__ __align__(16) unsigned char As[128 * 128];
    __shared__ __align__(16) unsigned char Bs[128 * 128];

    const int z = blockIdx.z;
    const bool isV = (z >= 8);
    const int b = z & 7;
    const int kc_b = cnts[b * 2];
    const int m0 = blockIdx.y * 128;
    if (m0 >= rup(kc_b, 128)) return;
    const int n0 = blockIdx.x * 128;
    const int tid = threadIdx.x, lane = tid & 63, wid = tid >> 6;
    const int wm = (wid >> 1) * 64, wn = (wid & 1) * 64;

    const u16* Ab = (isV ? Vc : Xkc) + (size_t)b * Ln * Dn;
    const u16* Bb = isV ? Wvb : Mb;
    u16* Cb = (isV ? Vhc : Gt) + (size_t)b * Ln * Dn;

    const u16* gA[4]; const u16* gB[4]; int ldsOff[4];
    #pragma unroll
    for (int q = 0; q < 4; ++q) {
        int c = wid * 4 + q;
        int row = c * 8 + (lane >> 3);
        int sig = (lane & 7) ^ (row & 7);
        gA[q] = Ab + (size_t)(m0 + row) * Dn + sig * 8;
        gB[q] = Bb + (size_t)(n0 + row) * Dn + sig * 8;
        ldsOff[q] = c * 1024;
    }

    f32x4 acc[4][4];
    const f32x4 z4 = {0.f, 0.f, 0.f, 0.f};
    #pragma unroll
    for (int i = 0; i < 4; ++i)
        #pragma unroll
        for (int j = 0; j < 4; ++j) acc[i][j] = z4;

    for (int k0 = 0; k0 < Dn; k0 += 64) {
        #pragma unroll
        for (int q = 0; q < 4; ++q) {
            gload16(gA[q], As + ldsOff[q]);
            gload16(gB[q], Bs + ldsOff[q]);
            gA[q] += 64; gB[q] += 64;
        }
        __syncthreads();

        const int sh = lane >> 4;
        #pragma unroll
        for (int s = 0; s < 2; ++s) {
            bf16x8 af[4], bf[4];
            #pragma unroll
            for (int i = 0; i < 4; ++i) {
                int row = wm + i * 16 + (lane & 15);
                af[i] = *(const bf16x8*)(As + row * 128 + (((s * 4 + sh) ^ (row & 7)) << 4));
            }
            #pragma unroll
            for (int j = 0; j < 4; ++j) {
                int row = wn + j * 16 + (lane & 15);
                bf[j] = *(const bf16x8*)(Bs + row * 128 + (((s * 4 + sh) ^ (row & 7)) << 4));
            }
            #pragma unroll
            for (int i = 0; i < 4; ++i)
                #pragma unroll
                for (int j = 0; j < 4; ++j)
                    acc[i][j] = MFMA16(af[i], bf[j], acc[i][j]);
        }
        __syncthreads();
    }

    float bv4[4];
    #pragma unroll
    for (int j = 0; j < 4; ++j)
        bv4[j] = isV ? bv[n0 + wn + j * 16 + (lane & 15)] : 0.0f;
    #pragma unroll
    for (int i = 0; i < 4; ++i) {
        #pragma unroll
        for (int r = 0; r < 4; ++r) {
            int m = m0 + wm + i * 16 + (lane >> 4) * 4 + r;
            u16* oh = Cb + (size_t)m * Dn + n0 + wn;
            #pragma unroll
            for (int j = 0; j < 4; ++j) {
                float val = acc[i][j][r];
                if (isV) val += bv4[j];
                oh[j * 16 + (lane & 15)] = f2bf(val);
            }
        }
    }
}

// ---------------------------------------------------------------------------
// scoremix: blocks [0,2048) = scorec (XCD-chunked); blocks [2048,6144) =
// vtransc (straight transpose of compacted Vhc). Both depend only on
// {gtpv, convmix} -> one launch; transpose blocks fill scorec's tail.
// ---------------------------------------------------------------------------
__global__ __launch_bounds__(256) void scoremix_kernel(
    const u16* __restrict__ Xq, const u16* __restrict__ Gt,
    const u16* __restrict__ Vhc, const int* __restrict__ cnts,
    const float* __restrict__ u, const float* __restrict__ vc,
    u16* __restrict__ Ec, u16* __restrict__ Vtc)
{
    __shared__ __align__(16) unsigned char As[128 * 128];
    __shared__ __align__(16) unsigned char Bs[128 * 128];

    const int blk = blockIdx.x;
    const int tid = threadIdx.x;

    if (blk >= 2048) {
        // ---- vtransc part ----
        u16 (*tile)[72] = (u16(*)[72])As;   // 9216 B <= 16384 B
        const int rel = blk - 2048;
        const int b = rel >> 9;             // 8 batches x 512 tiles
        const int l0 = ((rel >> 4) & 31) * 64, d0 = (rel & 15) * 64;
        if (l0 >= rup(cnts[b * 2], 64)) return;
        const int r = tid >> 2, cq = (tid & 3) * 16;

        const u16* src = Vhc + (size_t)(b * Ln + l0 + r) * Dn + d0 + cq;
        *(uint4*)&tile[r][cq]     = *(const uint4*)(src);
        *(uint4*)&tile[r][cq + 8] = *(const uint4*)(src + 8);
        __syncthreads();

        u16 tmp[16];
        #pragma unroll
        for (int i = 0; i < 16; ++i) tmp[i] = tile[cq + i][r];
        u16* dst = Vtc + (size_t)b * Dn * Ln + (size_t)(d0 + r) * Ln + l0 + cq;
        *(uint4*)(dst)     = *(uint4*)&tmp[0];
        *(uint4*)(dst + 8) = *(uint4*)&tmp[8];
        return;
    }

    // ---- scorec part ----
    // swizzle: nwg = 2048 = 8 * 256
    const int d = blk;
    const int f = (d & 7) * 256 + (d >> 3);
    const int b = f >> 8;
    const int rem = f & 255;
    const int m0 = (rem >> 4) * 128;  // 16 q-tiles
    const int n0 = (rem & 15) * 128;  // 16 k-tiles

    const int kc_b = cnts[b * 2];
    if (n0 >= kc_b) return;
    const int lane = tid & 63, wid = tid >> 6;
    const int wm = (wid >> 1) * 64, wn = (wid & 1) * 64;

    const size_t boff = (size_t)b * Ln * Dn;
    const u16* Xq_b = Xq + boff;
    const u16* Gt_b = Gt + boff;

    const u16* gA[4]; const u16* gB[4]; int ldsOff[4];
    #pragma unroll
    for (int q = 0; q < 4; ++q) {
        int c = wid * 4 + q;
        int row = c * 8 + (lane >> 3);
        int sig = (lane & 7) ^ (row & 7);
        gA[q] = Xq_b + (size_t)(m0 + row) * Dn + sig * 8;
        gB[q] = Gt_b + (size_t)(n0 + row) * Dn + sig * 8;
        ldsOff[q] = c * 1024;
    }

    f32x4 acc[4][4];
    const f32x4 z4 = {0.f, 0.f, 0.f, 0.f};
    #pragma unroll
    for (int i = 0; i < 4; ++i)
        #pragma unroll
        for (int j = 0; j < 4; ++j) acc[i][j] = z4;

    for (int k0 = 0; k0 < Dn; k0 += 64) {
        #pragma unroll
        for (int q = 0; q < 4; ++q) {
            gload16(gA[q], As + ldsOff[q]);
            gload16(gB[q], Bs + ldsOff[q]);
            gA[q] += 64; gB[q] += 64;
        }
        __syncthreads();

        const int sh = lane >> 4;
        #pragma unroll
        for (int s = 0; s < 2; ++s) {
            bf16x8 af[4], bf[4];
            #pragma unroll
            for (int i = 0; i < 4; ++i) {
                int row = wm + i * 16 + (lane & 15);
                af[i] = *(const bf16x8*)(As + row * 128 + (((s * 4 + sh) ^ (row & 7)) << 4));
            }
            #pragma unroll
            for (int j = 0; j < 4; ++j) {
                int row = wn + j * 16 + (lane & 15);
                bf[j] = *(const bf16x8*)(Bs + row * 128 + (((s * 4 + sh) ^ (row & 7)) << 4));
            }
            #pragma unroll
            for (int i = 0; i < 4; ++i)
                #pragma unroll
                for (int j = 0; j < 4; ++j)
                    acc[i][j] = MFMA16(af[i], bf[j], acc[i][j]);
        }
        __syncthreads();
    }

    float vcl[4];
    #pragma unroll
    for (int j = 0; j < 4; ++j) vcl[j] = vc[b * Ln + n0 + wn + j * 16 + (lane & 15)];
    #pragma unroll
    for (int i = 0; i < 4; ++i) {
        #pragma unroll
        for (int r = 0; r < 4; ++r) {
            int m = m0 + wm + i * 16 + (lane >> 4) * 4 + r;
            float um = u[b * Ln + m];
            u16* orow = Ec + ((size_t)(b * Ln + m)) * Ln + n0 + wn;
            #pragma unroll
            for (int j = 0; j < 4; ++j) {
                int jj = n0 + wn + j * 16 + (lane & 15);
                orow[j * 16 + (lane & 15)] =
                    f2bf((jj < kc_b) ? (acc[i][j][r] + um + vcl[j]) : MASKED_VAL);
            }
        }
    }
}

// ---------------------------------------------------------------------------
// stats_expand: one block per (b,q) row.
// If q-unmasked: block-reduce max/sum, write bf16 P row (q-compacted layout).
// Else: zero the out_a row.
// Always: expand bf16 Ec row -> full masked f32 e row (kpos gather).
// ---------------------------------------------------------------------------
__global__ __launch_bounds__(256) void stats_expand_kernel(
    const u16* __restrict__ Ec, const int* __restrict__ kpos,
    const int* __restrict__ qpos, const int* __restrict__ cnts,
    u16* __restrict__ Pc, float* __restrict__ e, float* __restrict__ out_a)
{
    __shared__ float redm[4];
    __shared__ float reds[4];
    const int row = blockIdx.x;
    const int b = row >> 11;
    const int t = threadIdx.x;
    const u16* er = Ec + (size_t)row * Ln;
    const int qp = qpos[row];

    if (qp >= 0) {
        const int bound = rup(cnts[b * 2], 64);
        const int lane = t & 63, wave = t >> 6;
        float v[8];
        int base = t * 8;
        if (base < bound) {
            uint4 x = *(const uint4*)(er + base);
            const u16* xs = (const u16*)&x;
            #pragma unroll
            for (int j = 0; j < 8; ++j) v[j] = bf2f(xs[j]);
        } else {
            #pragma unroll
            for (int j = 0; j < 8; ++j) v[j] = MASKED_VAL;
        }

        float mx = v[0];
        #pragma unroll
        for (int j = 1; j < 8; ++j) mx = fmaxf(mx, v[j]);
        #pragma unroll
        for (int o = 32; o > 0; o >>= 1) mx = fmaxf(mx, __shfl_xor(mx, o, 64));
        if (lane == 0) redm[wave] = mx;
        __syncthreads();
        mx = fmaxf(fmaxf(redm[0], redm[1]), fmaxf(redm[2], redm[3]));

        float s = 0.f;
        #pragma unroll
        for (int j = 0; j < 8; ++j) s += __expf(v[j] - mx);
        #pragma unroll
        for (int o = 32; o > 0; o >>= 1) s += __shfl_xor(s, o, 64);
        if (lane == 0) reds[wave] = s;
        __syncthreads();
        s = reds[0] + reds[1] + reds[2] + reds[3];
        float sinv = 1.0f / s;

        u32 P[4];
        #pragma unroll
        for (int j = 0; j < 4; ++j)
            P[j] = pack2(__expf(v[2*j] - mx) * sinv, __expf(v[2*j+1] - mx) * sinv);
        u16* pr = Pc + ((size_t)b * Ln + qp) * Ln + t * 8;
        *(uint4*)pr = make_uint4(P[0], P[1], P[2], P[3]);
    } else {
        *(float4*)(out_a + (size_t)row * Dn + t * 4) = make_float4(0.f, 0.f, 0.f, 0.f);
    }

    // expansion (reads Ec, writes e; independent of P path)
    const int* kp = kpos + b * Ln;
    const int k = t * 8;
    int p[8];
    *(int4*)&p[0] = *(const int4*)(kp + k);
    *(int4*)&p[4] = *(const int4*)(kp + k + 4);
    float o[8];
    #pragma unroll
    for (int j = 0; j < 8; ++j)
        o[j] = (p[j] >= 0) ? bf2f(er[p[j]]) : MASKED_VAL;

    float* eo = e + (size_t)row * Ln + k;
    *(float4*)(eo)     = make_float4(o[0], o[1], o[2], o[3]);
    *(float4*)(eo + 4) = make_float4(o[4], o[5], o[6], o[7]);
}

// ---------------------------------------------------------------------------
// pvc: a[qidx[i], :] = Pc[b,i,:] @ Vtc^T over compacted k. Pure GEMM.
// XCD-chunked grid (1024).
// ---------------------------------------------------------------------------
__global__ __launch_bounds__(256) void pvc_kernel(
    const u16* __restrict__ Pc, const u16* __restrict__ Vtc,
    const int* __restrict__ qidx, const int* __restrict__ cnts,
    float* __restrict__ out_a)
{
    __shared__ __align__(16) unsigned char As[128 * 128];
    __shared__ __align__(16) unsigned char Bs[128 * 128];

    // swizzle: nwg = 1024 = 8 * 128
    const int d = blockIdx.x;
    const int f = (d & 7) * 128 + (d >> 3);
    const int b = f >> 7;
    const int rem = f & 127;
    const int m0 = (rem >> 3) * 128;  // 16 compacted q tiles
    const int n0 = (rem & 7) * 128;   // 8 d tiles

    const int kc_b = cnts[b * 2], qc_b = cnts[b * 2 + 1];
    if (m0 >= rup(qc_b, 128)) return;
    const int kbound = rup(kc_b, 64);
    const int tid = threadIdx.x, lane = tid & 63, wid = tid >> 6;
    const int wm = (wid >> 1) * 64, wn = (wid & 1) * 64;

    const u16* Pc_b  = Pc  + (size_t)b * Ln * Ln;
    const u16* Vtc_b = Vtc + (size_t)b * Dn * Ln;
    const int* qidx_b = qidx + b * Ln;

    const u16* gA[4]; const u16* gB[4]; int ldsOff[4];
    #pragma unroll
    for (int q = 0; q < 4; ++q) {
        int c = wid * 4 + q;
        int row = c * 8 + (lane >> 3);
        int sig = (lane & 7) ^ (row & 7);
        gA[q] = Pc_b  + (size_t)(m0 + row) * Ln + sig * 8;
        gB[q] = Vtc_b + (size_t)(n0 + row) * Ln + sig * 8;
        ldsOff[q] = c * 1024;
    }

    f32x4 acc[4][4];
    const f32x4 z4 = {0.f, 0.f, 0.f, 0.f};
    #pragma unroll
    for (int i = 0; i < 4; ++i)
        #pragma unroll
        for (int j = 0; j < 4; ++j) acc[i][j] = z4;

    for (int k0 = 0; k0 < kbound; k0 += 64) {
        #pragma unroll
        for (int q = 0; q < 4; ++q) {
            gload16(gA[q], As + ldsOff[q]);
            gload16(gB[q], Bs + ldsOff[q]);
            gA[q] += 64; gB[q] += 64;
        }
        __syncthreads();

        const int sh = lane >> 4;
        #pragma unroll
        for (int s = 0; s < 2; ++s) {
            bf16x8 af[4], bv[4];
            #pragma unroll
            for (int i = 0; i < 4; ++i) {
                int row = wm + i * 16 + (lane & 15);
                af[i] = *(const bf16x8*)(As + row * 128 + (((s * 4 + sh) ^ (row & 7)) << 4));
            }
            #pragma unroll
            for (int j = 0; j < 4; ++j) {
                int row = wn + j * 16 + (lane & 15);
                bv[j] = *(const bf16x8*)(Bs + row * 128 + (((s * 4 + sh) ^ (row & 7)) << 4));
            }
            #pragma unroll
            for (int i = 0; i < 4; ++i)
                #pragma unroll
                for (int j = 0; j < 4; ++j)
                    acc[i][j] = MFMA16(af[i], bv[j], acc[i][j]);
        }
        __syncthreads();
    }

    #pragma unroll
    for (int i = 0; i < 4; ++i) {
        #pragma unroll
        for (int r = 0; r < 4; ++r) {
            int gi = m0 + wm + i * 16 + (lane >> 4) * 4 + r;
            if (gi < qc_b) {
                int gm = qidx_b[gi];
                float* orow = out_a + (size_t)(b * Ln + gm) * Dn + n0 + wn;
                #pragma unroll
                for (int j = 0; j < 4; ++j)
                    orow[j * 16 + (lane & 15)] = acc[i][j][r];
            }
        }
    }
}

// ---------------------------------------------------------------------------
extern "C" void kernel_launch(void* const* d_in, const int* in_sizes, int n_in,
                              void* d_out, int out_size, void* d_ws, size_t ws_size,
                              hipStream_t stream)
{
    const float* Q  = (const float*)d_in[0];
    const float* K  = (const float*)d_in[1];
    const float* V  = (const float*)d_in[2];
    const float* Wq = (const float*)d_in[3];
    const float* bq = (const float*)d_in[4];
    const float* Wk = (const float*)d_in[5];
    const float* bk = (const float*)d_in[6];
    const float* Wv = (const float*)d_in[7];
    const float* bv = (const float*)d_in[8];
    const int* q_mask = (const int*)d_in[9];
    const int* k_mask = (const int*)d_in[10];

    float* out_a = (float*)d_out;                       // [B, L, D]
    float* out_e = out_a + (size_t)Bn * Ln * Dn;        // [B, L, L]

    const size_t NE = (size_t)Bn * Ln * Dn;             // 16,777,216
    const size_t NW = (size_t)Dn * Dn;                  // 1,048,576
    const int BL = Bn * Ln;                             // 16,384

    // ws layout (aliasing plan):
    //   [Vc, Xkc]  -> aliased by Ec (bf16 e', 2*NE) after both are dead
    //   [Gt, Vhc]  -> aliased by Pc (bf16 P,  2*NE) after both are dead
    //   Xq, Vtc, Wvb, Wqt, Wkt, Mb, small tables
    u16* Vc  = (u16*)d_ws;
    u16* Xkc = Vc + NE;
    u16* Gt  = Xkc + NE;
    u16* Vhc = Gt + NE;
    u16* Xq  = Vhc + NE;
    u16* Vtc = Xq + NE;
    u16* Wvb = Vtc + NE;
    u16* Wqt = Wvb + NW;
    u16* Wkt = Wqt + NW;
    u16* Mb  = Wkt + NW;
    float* w1    = (float*)(Mb + NW);
    float* w2    = w1 + Dn;
    float* cbuf  = w2 + Dn;
    float* uarr  = cbuf + 4;
    float* vc    = uarr + BL;
    int* kidx = (int*)(vc + BL);
    int* kpos = kidx + BL;
    int* qidx = kpos + BL;
    int* qpos = qidx + BL;
    int* cnts = qpos + BL;

    u16* Ec = Vc;   // [B][L][L] bf16, aliases Vc+Xkc (dead after gtpv)
    u16* Pc = Gt;   // [B][L][L] bf16 (q-compacted rows), aliases Gt+Vhc

    dim3 blk(256);

    // 0) fused prep + weight prep
    prepw_kernel<<<dim3(1033), blk, 0, stream>>>(
        k_mask, q_mask, Wq, Wk, Wv, bq, bk,
        kidx, kpos, qidx, qpos, cnts, Wqt, Wkt, Wvb, cbuf);

    // 1) fused mgemm (Mb = Wq^T Wk) + wvec (w1/w2)
    wmix_kernel<<<dim3(576), blk, 0, stream>>>(Wqt, Wkt, bk, bq, w1, w2, Mb);

    // 2) fused convert Q (+u) and gathered K/V (+vc)
    convmix_kernel<<<dim3(49152), blk, 0, stream>>>(
        Q, K, V, kidx, cnts, w1, w2, cbuf, Xq, Xkc, Vc, uarr, vc);

    // 3) fused Gt = Xkc@M^T and Vhc = Vc@Wv^T + bv (compacted rows)
    gtpv_kernel<<<dim3(Dn / 128, Ln / 128, 16), blk, 0, stream>>>(
        Xkc, Vc, Mb, Wvb, bv, cnts, Gt, Vhc);

    // 4) fused compacted scores -> Ec  +  V transpose -> Vtc
    scoremix_kernel<<<dim3(2048 + 4096), blk, 0, stream>>>(
        Xq, Gt, Vhc, cnts, uarr, vc, Ec, Vtc);

    // 5) fused stats + bf16 P emission + e expand + masked-q a zeroing
    stats_expand_kernel<<<dim3(BL), blk, 0, stream>>>(
        Ec, kpos, qpos, cnts, Pc, out_e, out_a);

    // 6) pure-GEMM PV
    pvc_kernel<<<dim3(1024), blk, 0, stream>>>(Pc, Vtc, qidx, cnts, out_a);
}